// Round 7
// baseline (1152.772 us; speedup 1.0000x reference)
//
#include <hip/hip_runtime.h>
#include <math.h>

// Problem constants
#define B_     32
#define F_     64
#define T_     518
#define HID    64
#define GATES  256   // 4*HID
#define CCH    128   // 2*HID lstm output channels
#define NWAVE  6
#define WCH    768   // NWAVE*CCH
#define L2_    516   // T-2   (conv2 out)
#define L3_    512   // L2-4  (conv3 out)
#define L4_    510   // L3-2  (conv4/conv5 out)

typedef float v2f __attribute__((ext_vector_type(2)));

__device__ __forceinline__ float frcp(float x) { return __builtin_amdgcn_rcpf(x); }
__device__ __forceinline__ float fsigmoid(float x) { return frcp(1.f + __expf(-x)); }
__device__ __forceinline__ float ftanh(float x) { return 1.f - 2.f * frcp(1.f + __expf(2.f * x)); }

// ---------------------------------------------------------------------------
// K1: input projections, both dirs. Output layout xg[t][w][r][g2] (coalesced).
// (R0-proven variant.)
__global__ void xg_kernel(const float* __restrict__ x,
                          const float* __restrict__ wif, const float* __restrict__ bf,
                          const float* __restrict__ wir, const float* __restrict__ br,
                          float* __restrict__ xg_f, float* __restrict__ xg_r,
                          float* __restrict__ stats) {
    if (blockIdx.x == 0 && blockIdx.y == 0) {
        for (int i = threadIdx.x; i < 2 * WCH; i += 256) stats[i] = 0.f;
    }
    const int tid = threadIdx.x;
    const int wv  = tid >> 7;
    const int g2  = tid & 1;
    const int r   = (tid >> 1) & 63;
    const int g   = (2 * wv + g2) * 64 + r;       // gate row; store offset == tid
    const int b   = blockIdx.y;
    const int t0  = blockIdx.x * 8;
    float4 wa[16], wb[16];
    const float4* w0 = (const float4*)(wif + g * F_);
    const float4* w1 = (const float4*)(wir + g * F_);
#pragma unroll
    for (int i = 0; i < 16; ++i) { wa[i] = w0[i]; wb[i] = w1[i]; }
    const float bfv = bf[g], brv = br[g];
    for (int tt = 0; tt < 8; ++tt) {
        const int t = t0 + tt;
        if (t >= T_) break;
        const float* xp = x + (size_t)b * F_ * T_ + t;
        float a0 = bfv, a1 = brv;
#pragma unroll
        for (int i = 0; i < 16; ++i) {
            float x0 = xp[(i * 4 + 0) * T_];
            float x1 = xp[(i * 4 + 1) * T_];
            float x2 = xp[(i * 4 + 2) * T_];
            float x3 = xp[(i * 4 + 3) * T_];
            a0 += wa[i].x * x0 + wa[i].y * x1 + wa[i].z * x2 + wa[i].w * x3;
            a1 += wb[i].x * x0 + wb[i].y * x1 + wb[i].z * x2 + wb[i].w * x3;
        }
        const size_t o = ((size_t)b * T_ + t) * GATES + tid;   // coalesced
        xg_f[o] = a0;
        xg_r[o] = a1;
    }
}

// ---------------------------------------------------------------------------
// K2: LSTM recurrence — R0 2-wave structure + LDS-RESIDENT weights.
// R6 post-mortem: register residency of Whh is unreachable (5 failed
// attempts; allocator caps ~150 live VGPRs and remats). Instead stage the
// 64 KB Whh into LDS once and read it there every step: same bytes/step,
// but LDS = 256 B/cy/CU + ~64 cy latency vs L2's ~60-85 B/cy + ~200 cy.
// Transposed layout wlds[k4][gate_row]: lane r reads row 128w+r -> word
// 4r mod 32 -> 8x4-bank groups, 8 words/bank = b128 floor (no swizzle).
// h reads are same-address broadcasts (free). grid(64), block 128.
__global__ __launch_bounds__(128, 1) void lstm_kernel(
        const float* __restrict__ xgi_f, const float* __restrict__ xgi_r,
        const float* __restrict__ whf, const float* __restrict__ whr,
        float* __restrict__ X) {
    const int dir = blockIdx.x & 1;
    const int b   = blockIdx.x >> 1;
    const float* xg  = (dir ? xgi_r : xgi_f) + (size_t)b * T_ * GATES;
    const float* whh = dir ? whr : whf;
    const int tid = threadIdx.x;
    const int r   = tid & 63;
    const int w   = tid >> 6;            // wave 0: gates i,f ; wave 1: gates g,o

    __shared__ __align__(16) float4 wlds[16][GATES];  // 64 KB, [k4][gate_row]
    __shared__ __align__(16) float hs[2][HID];        // per-wave private h
    __shared__ __align__(16) float gbuf[2][HID][4];   // double-buffered gates

    // One-time stage: wlds[i][g] = Whh[g][4i..4i+3]
    for (int g = tid; g < GATES; g += 128) {
        const float4* src = (const float4*)(whh + (size_t)g * HID);
#pragma unroll
        for (int i = 0; i < 16; ++i) wlds[i][g] = src[i];
    }
    hs[w][r] = 0.f;
    float c = 0.f;
    float* Xrow = X + ((size_t)(b * CCH + dir * HID + r)) * T_;

    int t = dir ? (T_ - 1) : 0;
    const int step = dir ? -1 : 1;
    const float2* xg2 = (const float2*)xg;   // index (t*2 + w)*64 + r
    float2 q0 = xg2[((size_t)t * 2 + w) * 64 + r];
    float2 q1 = xg2[((size_t)(t + step) * 2 + w) * 64 + r];
    __syncthreads();                          // staging visible to both waves

    const float4* wArow = &wlds[0][128 * w + r];        // + i*GATES per k4
    const float4* wBrow = &wlds[0][128 * w + 64 + r];

    for (int s = 0; s < T_; ++s) {
        float4 a0 = {q0.x, 0.f, 0.f, 0.f};
        float4 a1 = {q0.y, 0.f, 0.f, 0.f};
        const float4* h4p = (const float4*)hs[w];
#pragma unroll
        for (int i = 0; i < 16; ++i) {
            const float4 h4 = h4p[i];
            const float4 wa = wArow[i * GATES];
            const float4 wb = wBrow[i * GATES];
            a0.x = fmaf(wa.x, h4.x, a0.x); a0.y = fmaf(wa.y, h4.y, a0.y);
            a0.z = fmaf(wa.z, h4.z, a0.z); a0.w = fmaf(wa.w, h4.w, a0.w);
            a1.x = fmaf(wb.x, h4.x, a1.x); a1.y = fmaf(wb.y, h4.y, a1.y);
            a1.z = fmaf(wb.z, h4.z, a1.z); a1.w = fmaf(wb.w, h4.w, a1.w);
        }
        const float gA = (a0.x + a0.y) + (a0.z + a0.w);
        const float gB = (a1.x + a1.y) + (a1.z + a1.w);
        const int buf = s & 1;
        *(float2*)&gbuf[buf][r][2 * w] = make_float2(gA, gB);

        int tp = t + 2 * step;
        tp = tp < 0 ? 0 : (tp >= T_ ? T_ - 1 : tp);
        const float2 qn = xg2[((size_t)tp * 2 + w) * 64 + r];

        asm volatile("s_waitcnt lgkmcnt(0)" ::: "memory");
        __builtin_amdgcn_s_barrier();

        const float4 g4 = *(const float4*)gbuf[buf][r];   // i,f,g,o
        const float si = fsigmoid(g4.x);
        const float sf = fsigmoid(g4.y);
        const float so = fsigmoid(g4.w);
        c = sf * c + si * ftanh(g4.z);
        const float h = so * ftanh(c);

        hs[w][r] = h;
        if (w == 0) Xrow[t] = h;
        q0 = q1; q1 = qn;
        t += step;
    }
}

// ---------------------------------------------------------------------------
// K3: wave module + fused BN1 partial stats. grid(3, 128, 32), block 256
__global__ void wave_kernel(const float* __restrict__ X,
                            const float* __restrict__ bw, const float* __restrict__ bb,
                            float* __restrict__ wave, float* __restrict__ stats) {
    const int b = blockIdx.z, c = blockIdx.y;
    const int t0 = blockIdx.x * 256;
    const int tid = threadIdx.x;
    __shared__ float xs[256 + 14];
    __shared__ float bws[NWAVE][16];
    __shared__ float bbs[NWAVE];
    __shared__ float red[4][12];
    const float* xrow = X + ((size_t)(b * CCH + c)) * T_;
    for (int i = tid; i < 270; i += 256) {
        int tt = t0 - 7 + i;
        xs[i] = (tt >= 0 && tt < T_) ? xrow[tt] : 0.f;
    }
    if (tid < NWAVE * 15) bws[tid / 15][tid % 15] = bw[tid];
    if (tid < NWAVE) bbs[tid] = bb[tid];
    __syncthreads();
    const int t = t0 + tid;
    float ls[NWAVE], lq[NWAVE];
#pragma unroll
    for (int ii = 0; ii < NWAVE; ++ii) { ls[ii] = 0.f; lq[ii] = 0.f; }
    if (t < T_) {
        float win[15];
#pragma unroll
        for (int k = 0; k < 15; ++k) win[k] = xs[tid + k];
        float e[8];
        e[0] = win[7];
#pragma unroll
        for (int m = 1; m < 8; ++m) e[m] = win[7 - m] + win[7 + m];
        const float c0 = 6.28318530717958647692f / 15.f;  // 2*pi/WIDE
#pragma unroll
        for (int ii = 0; ii < NWAVE; ++ii) {
            float sc = bbs[ii];
#pragma unroll
            for (int k = 0; k < 15; ++k) sc += win[k] * bws[ii][k];
            sc = fmaxf(sc, 0.f);
            const float phi = c0 * (float)(ii + 1) * sc;
            float o = e[0];
#pragma unroll
            for (int m = 1; m < 8; ++m) o += e[m] * __cosf(phi * (float)m);
            const float q = (truncf(sc * 15.f) + 1.f) * (2.f / 17.f);
            const float val = o * rsqrtf(q);
            wave[((size_t)(b * WCH + ii * CCH + c)) * T_ + t] = val;
            ls[ii] = val;
            lq[ii] = val * val;
        }
    }
#pragma unroll
    for (int off = 32; off > 0; off >>= 1) {
#pragma unroll
        for (int ii = 0; ii < NWAVE; ++ii) {
            ls[ii] += __shfl_down(ls[ii], off);
            lq[ii] += __shfl_down(lq[ii], off);
        }
    }
    if ((tid & 63) == 0) {
        const int w = tid >> 6;
#pragma unroll
        for (int ii = 0; ii < NWAVE; ++ii) { red[w][ii] = ls[ii]; red[w][6 + ii] = lq[ii]; }
    }
    __syncthreads();
    if (tid < 12) {
        const float a = red[0][tid] + red[1][tid] + red[2][tid] + red[3][tid];
        const int ii = tid % 6;
        const int ch = ii * CCH + c;
        atomicAdd(&stats[(tid >= 6 ? WCH : 0) + ch], a);
    }
}

// Finalize BN1 stats: 1 block, 768 threads
__global__ void bn1_finalize_kernel(const float* __restrict__ stats,
                                    float* __restrict__ mean, float* __restrict__ rstd) {
    const int c = threadIdx.x;
    const float n = (float)(B_ * T_);
    const float m = stats[c] / n;
    const float v = stats[WCH + c] / n - m * m;
    mean[c] = m;
    rstd[c] = rsqrtf(v + 1e-5f);
}

// ---------------------------------------------------------------------------
// Generic training-mode BN statistics: one block per channel
__global__ void bn_stats_kernel(const float* __restrict__ x, int Bn, int C, int L,
                                float* __restrict__ mean, float* __restrict__ rstd) {
    const int c = blockIdx.x;
    const int tid = threadIdx.x;
    float s = 0.f, s2 = 0.f;
    for (int b = 0; b < Bn; ++b) {
        const float* row = x + ((size_t)b * C + c) * L;
        for (int l = tid; l < L; l += 256) { float v = row[l]; s += v; s2 += v * v; }
    }
#pragma unroll
    for (int off = 32; off > 0; off >>= 1) { s += __shfl_down(s, off); s2 += __shfl_down(s2, off); }
    __shared__ float ss[4], ss2[4];
    if ((tid & 63) == 0) { ss[tid >> 6] = s; ss2[tid >> 6] = s2; }
    __syncthreads();
    if (tid == 0) {
        float S = ss[0] + ss[1] + ss[2] + ss[3];
        float S2 = ss2[0] + ss2[1] + ss2[2] + ss2[3];
        float n = (float)(Bn * L);
        float m = S / n;
        float v = S2 / n - m * m;
        mean[c] = m;
        rstd[c] = rsqrtf(v + 1e-5f);
    }
}

// ---------------------------------------------------------------------------
// BN-fold transforms: w'[c,k,o] = w[o,c,k]*sc[c]; b'[o] = b[o] + sum w*sh[c].
// bnfold2: grid(128), block 256 (one block per output channel)
__global__ void bnfold2_kernel(const float* __restrict__ w2, const float* __restrict__ b2,
                               const float* __restrict__ m1, const float* __restrict__ r1,
                               const float* __restrict__ g1, const float* __restrict__ be1,
                               float* __restrict__ w2t, float* __restrict__ b2t) {
    const int o = blockIdx.x, tid = threadIdx.x;
    float part = 0.f;
    for (int idx = tid; idx < WCH * 3; idx += 256) {
        const int c = idx / 3;
        const float sc = r1[c] * g1[c];
        const float sh = be1[c] - m1[c] * sc;
        const float wv = w2[(size_t)o * (WCH * 3) + idx];
        w2t[(size_t)idx * 128 + o] = wv * sc;
        part += wv * sh;
    }
#pragma unroll
    for (int off = 32; off > 0; off >>= 1) part += __shfl_down(part, off);
    __shared__ float red[4];
    if ((tid & 63) == 0) red[tid >> 6] = part;
    __syncthreads();
    if (tid == 0) b2t[o] = b2[o] + red[0] + red[1] + red[2] + red[3];
}

// bnfold3: grid(32), block 256
__global__ void bnfold3_kernel(const float* __restrict__ w3, const float* __restrict__ b3,
                               const float* __restrict__ m2, const float* __restrict__ r2,
                               const float* __restrict__ g2, const float* __restrict__ be2,
                               float* __restrict__ w3t, float* __restrict__ b3t) {
    const int o = blockIdx.x, tid = threadIdx.x;
    float part = 0.f;
    for (int idx = tid; idx < 128 * 5; idx += 256) {
        const int c = idx / 5;
        const float sc = r2[c] * g2[c];
        const float sh = be2[c] - m2[c] * sc;
        const float wv = w3[(size_t)o * 640 + idx];
        w3t[(size_t)idx * 32 + o] = wv * sc;
        part += wv * sh;
    }
#pragma unroll
    for (int off = 32; off > 0; off >>= 1) part += __shfl_down(part, off);
    __shared__ float red[4];
    if ((tid & 63) == 0) red[tid >> 6] = part;
    __syncthreads();
    if (tid == 0) b3t[o] = b3[o] + red[0] + red[1] + red[2] + red[3];
}

// bnfold4: grid(16), block 128. Block 0 also emits BN3 affine (sc,sh) for dwt.
__global__ void bnfold4_kernel(const float* __restrict__ w4, const float* __restrict__ b4,
                               const float* __restrict__ m3, const float* __restrict__ r3,
                               const float* __restrict__ g3, const float* __restrict__ be3,
                               float* __restrict__ w4t, float* __restrict__ b4t,
                               float* __restrict__ bnp3) {
    const int o = blockIdx.x, tid = threadIdx.x;
    float part = 0.f;
    if (tid < 96) {
        const int c = tid / 3;
        const float sc = r3[c] * g3[c];
        const float sh = be3[c] - m3[c] * sc;
        const float wv = w4[(size_t)o * 96 + tid];
        w4t[(size_t)tid * 16 + o] = wv * sc;
        part = wv * sh;
    }
    if (o == 0 && tid >= 96) {
        const int ch = tid - 96;
        const float sc = r3[ch] * g3[ch];
        bnp3[ch] = sc;
        bnp3[32 + ch] = be3[ch] - m3[ch] * sc;
    }
#pragma unroll
    for (int off = 32; off > 0; off >>= 1) part += __shfl_down(part, off);
    __shared__ float red[2];
    if ((tid & 63) == 0) red[tid >> 6] = part;
    __syncthreads();
    if (tid == 0) b4t[o] = b4[o] + red[0] + red[1];
}

// ---------------------------------------------------------------------------
// conv2 (BN1 folded): wave_raw [32,768,518] -> relu -> y2 [32,128,516], k=3.
// v2f accumulators -> v_pk_fma_f32 halves the FMA issue. Weights [c][k][o].
// grid(32 b, 3 t, 8 o).
__global__ __launch_bounds__(256) void conv2_kernel(
        const float* __restrict__ in, const float* __restrict__ wt,
        const float* __restrict__ bt, float* __restrict__ out) {
    const int b  = blockIdx.x;
    const int t  = blockIdx.y * 256 + threadIdx.x;
    const int o0 = blockIdx.z * 16;
    if (t >= L2_) return;
    v2f acc[8];
    const v2f* bt2 = (const v2f*)(bt + o0);
#pragma unroll
    for (int j = 0; j < 8; ++j) acc[j] = bt2[j];
    const float* inb = in + (size_t)b * WCH * T_ + t;
    for (int c = 0; c < WCH; ++c) {
        const float x0 = inb[c * T_], x1 = inb[c * T_ + 1], x2 = inb[c * T_ + 2];
        const v2f vx0 = {x0, x0}, vx1 = {x1, x1}, vx2 = {x2, x2};
        const v2f* wc = (const v2f*)(wt + (size_t)c * 384 + o0);  // k-stride 64 v2f
#pragma unroll
        for (int j = 0; j < 8; ++j)
            acc[j] = __builtin_elementwise_fma(wc[j], vx0,
                     __builtin_elementwise_fma(wc[64 + j], vx1,
                     __builtin_elementwise_fma(wc[128 + j], vx2, acc[j])));
    }
    const size_t ob = ((size_t)b * 128 + o0) * L2_ + t;
#pragma unroll
    for (int j = 0; j < 8; ++j) {
        out[ob + (size_t)(2 * j) * L2_]     = fmaxf(acc[j].x, 0.f);
        out[ob + (size_t)(2 * j + 1) * L2_] = fmaxf(acc[j].y, 0.f);
    }
}

// conv3 (BN2 folded): y2_raw [32,128,516] -> relu -> y3 [32,32,512], k=5.
// grid(32 b, 2 t, 4 o), v2f accumulators, weights [c][k][o].
__global__ __launch_bounds__(256) void conv3_kernel(
        const float* __restrict__ in, const float* __restrict__ wt,
        const float* __restrict__ bt, float* __restrict__ out) {
    const int b  = blockIdx.x;
    const int t  = blockIdx.y * 256 + threadIdx.x;   // < 512 always
    const int o0 = blockIdx.z * 8;
    v2f acc[4];
    const v2f* bt2 = (const v2f*)(bt + o0);
#pragma unroll
    for (int j = 0; j < 4; ++j) acc[j] = bt2[j];
    const float* inb = in + (size_t)b * 128 * L2_ + t;
    for (int c = 0; c < 128; ++c) {
        const float x0 = inb[c * L2_], x1 = inb[c * L2_ + 1], x2 = inb[c * L2_ + 2];
        const float x3 = inb[c * L2_ + 3], x4 = inb[c * L2_ + 4];
        const v2f vx0 = {x0, x0}, vx1 = {x1, x1}, vx2 = {x2, x2}, vx3 = {x3, x3}, vx4 = {x4, x4};
        const v2f* wc = (const v2f*)(wt + (size_t)c * 160 + o0);  // k-stride 16 v2f
#pragma unroll
        for (int j = 0; j < 4; ++j)
            acc[j] = __builtin_elementwise_fma(wc[j], vx0,
                     __builtin_elementwise_fma(wc[16 + j], vx1,
                     __builtin_elementwise_fma(wc[32 + j], vx2,
                     __builtin_elementwise_fma(wc[48 + j], vx3,
                     __builtin_elementwise_fma(wc[64 + j], vx4, acc[j])))));
    }
    const size_t ob = ((size_t)b * 32 + o0) * L3_ + t;
#pragma unroll
    for (int j = 0; j < 4; ++j) {
        out[ob + (size_t)(2 * j) * L3_]     = fmaxf(acc[j].x, 0.f);
        out[ob + (size_t)(2 * j + 1) * L3_] = fmaxf(acc[j].y, 0.f);
    }
}

// conv4 (BN3 folded): y3_raw [32,32,512] -> relu -> y4 [32,16,510], k=3.
// grid(32 b, 2 t), block 256, v2f accumulators.
__global__ __launch_bounds__(256) void conv4_kernel(
        const float* __restrict__ in, const float* __restrict__ wt,
        const float* __restrict__ bt, float* __restrict__ out) {
    const int b = blockIdx.x;
    const int t = blockIdx.y * 256 + threadIdx.x;
    if (t >= L4_) return;
    v2f acc[8];
    const v2f* bt2 = (const v2f*)bt;
#pragma unroll
    for (int j = 0; j < 8; ++j) acc[j] = bt2[j];
    const float* inb = in + (size_t)b * 32 * L3_ + t;
    for (int c = 0; c < 32; ++c) {
        const float x0 = inb[c * L3_], x1 = inb[c * L3_ + 1], x2 = inb[c * L3_ + 2];
        const v2f vx0 = {x0, x0}, vx1 = {x1, x1}, vx2 = {x2, x2};
        const v2f* wc = (const v2f*)(wt + (size_t)c * 48);        // k-stride 8 v2f
#pragma unroll
        for (int j = 0; j < 8; ++j)
            acc[j] = __builtin_elementwise_fma(wc[j], vx0,
                     __builtin_elementwise_fma(wc[8 + j], vx1,
                     __builtin_elementwise_fma(wc[16 + j], vx2, acc[j])));
    }
    const size_t ob = ((size_t)b * 16) * L4_ + t;
#pragma unroll
    for (int j = 0; j < 8; ++j) {
        out[ob + (size_t)(2 * j) * L4_]     = fmaxf(acc[j].x, 0.f);
        out[ob + (size_t)(2 * j + 1) * L4_] = fmaxf(acc[j].y, 0.f);
    }
}

// Fused BN3(inline) + DWT bands + conv5 + relu -> y5 [32,16,510]. grid(32), block 512
__global__ __launch_bounds__(512) void dwt_conv5_kernel(const float* __restrict__ y3,
                                                        const float* __restrict__ w5,
                                                        const float* __restrict__ b5,
                                                        const float* __restrict__ bnp3,
                                                        float* __restrict__ y5) {
    const int b = blockIdx.x, l = threadIdx.x;  // l in [0,512)
    __shared__ float cm[L3_];
    __shared__ float bands[5][L3_];
    __shared__ float w5s[240];
    __shared__ float b5s[16];
    __shared__ float sc3s[32], sh3s[32];
    if (l < 240) w5s[l] = w5[l];
    if (l < 16) b5s[l] = b5[l];
    if (l >= 256 && l < 288) sc3s[l - 256] = bnp3[l - 256];
    if (l >= 288 && l < 320) sh3s[l - 288] = bnp3[32 + (l - 288)];
    __syncthreads();
    float s = 0.f, shs = 0.f;
    for (int ch = 0; ch < 32; ++ch) {
        s = fmaf(y3[((size_t)b * 32 + ch) * L3_ + l], sc3s[ch], s);
        shs += sh3s[ch];
    }
    cm[l] = (s + shs) * (1.f / 32.f);
    __syncthreads();
    const float s1 = 0.70710678118654752440f;
    const float s2c = 0.5f;
    const float s3 = 0.35355339059327378f;
    const float s4 = 0.25f;
    const int b16 = l & ~15, b8 = l & ~7, b4v = l & ~3, b2v = l & ~1;
    float sa = 0.f, sb = 0.f;
#pragma unroll
    for (int i = 0; i < 8; ++i) { sa += cm[b16 + i]; sb += cm[b16 + 8 + i]; }
    bands[0][l] = (sa + sb) * s4;
    bands[1][l] = (sa - sb) * s4;
    float ta = 0.f, tb = 0.f;
#pragma unroll
    for (int i = 0; i < 4; ++i) { ta += cm[b8 + i]; tb += cm[b8 + 4 + i]; }
    bands[2][l] = (ta - tb) * s3;
    bands[3][l] = (cm[b4v] + cm[b4v + 1] - cm[b4v + 2] - cm[b4v + 3]) * s2c;
    bands[4][l] = (cm[b2v] - cm[b2v + 1]) * s1;
    __syncthreads();
    if (l < L4_) {
        float in3[5][3];
#pragma unroll
        for (int c = 0; c < 5; ++c) {
            in3[c][0] = bands[c][l]; in3[c][1] = bands[c][l + 1]; in3[c][2] = bands[c][l + 2];
        }
#pragma unroll
        for (int o = 0; o < 16; ++o) {
            float acc = b5s[o];
#pragma unroll
            for (int c = 0; c < 5; ++c) {
                const float* wp = &w5s[(o * 5 + c) * 3];
                acc += in3[c][0] * wp[0] + in3[c][1] * wp[1] + in3[c][2] * wp[2];
            }
            y5[((size_t)b * 16 + o) * L4_ + l] = fmaxf(acc, 0.f);
        }
    }
}

// Tail stage A: per-(b,ch) sums/sumsq of y4 and y5. grid(32), block 512.
__global__ __launch_bounds__(512) void tail_partial_kernel(
        const float* __restrict__ y4, const float* __restrict__ y5,
        float* __restrict__ part) {
    const int b = blockIdx.x;
    const int p = threadIdx.x;
    const int ch = p >> 5;             // 16 channels
    const int sl = p & 31;             // 32 lanes per channel
    const float2* p4 = (const float2*)(y4 + ((size_t)(b * 16 + ch)) * L4_);
    const float2* p5 = (const float2*)(y5 + ((size_t)(b * 16 + ch)) * L4_);
    float s4 = 0.f, q4 = 0.f, s5 = 0.f, q5 = 0.f;
    for (int i = sl; i < L4_ / 2; i += 32) {
        float2 a = p4[i], e = p5[i];
        s4 += a.x + a.y;  q4 += a.x * a.x + a.y * a.y;
        s5 += e.x + e.y;  q5 += e.x * e.x + e.y * e.y;
    }
#pragma unroll
    for (int off = 16; off > 0; off >>= 1) {
        s4 += __shfl_down(s4, off, 32); q4 += __shfl_down(q4, off, 32);
        s5 += __shfl_down(s5, off, 32); q5 += __shfl_down(q5, off, 32);
    }
    if (sl == 0) {
        float4* o = (float4*)part;
        o[b * 16 + ch] = make_float4(s4, q4, s5, q5);
    }
}

// Tail stage B: BN4/BN5 stats + pooling(+affine) + FC. grid(1), block 512.
__global__ __launch_bounds__(512) void tail_final_kernel(
        const float* __restrict__ part,
        const float* __restrict__ g4, const float* __restrict__ be4,
        const float* __restrict__ g5, const float* __restrict__ be5,
        const float* __restrict__ fcw, const float* __restrict__ fcb,
        float* __restrict__ out) {
    const int p = threadIdx.x;           // 0..511
    const int b = p >> 4, ch = p & 15;
    const float4 v = ((const float4*)part)[b * 16 + ch];  // s4,q4,s5,q5
    __shared__ float S4[512], Q4[512], S5[512], Q5[512];
    __shared__ float M4[16], R4[16], M5[16], R5[16];
    __shared__ float pool[B_][16];
    S4[p] = v.x; Q4[p] = v.y; S5[p] = v.z; Q5[p] = v.w;
    __syncthreads();
    if (p < 16) {
        float ts = 0.f, tq = 0.f, us = 0.f, uq = 0.f;
        for (int bb = 0; bb < B_; ++bb) {
            ts += S4[bb * 16 + p]; tq += Q4[bb * 16 + p];
            us += S5[bb * 16 + p]; uq += Q5[bb * 16 + p];
        }
        const float n = (float)(B_ * L4_);
        float m = ts / n; M4[p] = m; R4[p] = rsqrtf(tq / n - m * m + 1e-5f);
        m = us / n;       M5[p] = m; R5[p] = rsqrtf(uq / n - m * m + 1e-5f);
    }
    __syncthreads();
    {
        const float mm4 = v.x / (float)L4_, mm5 = v.z / (float)L4_;
        const float v4 = (mm4 - M4[ch]) * R4[ch] * g4[ch] + be4[ch];
        const float v5 = (mm5 - M5[ch]) * R5[ch] * g5[ch] + be5[ch];
        pool[b][ch] = 0.5f * (v4 + v5);
    }
    __syncthreads();
    if (p < B_ * 10) {
        const int bb = p / 10, row = p - bb * 10;
        float a = fcb[row];
#pragma unroll
        for (int c = 0; c < 16; ++c) a += pool[bb][c] * fcw[row * 16 + c];
        out[bb * 10 + row] = a;
    }
}

// ---------------------------------------------------------------------------
extern "C" void kernel_launch(void* const* d_in, const int* in_sizes, int n_in,
                              void* d_out, int out_size, void* d_ws, size_t ws_size,
                              hipStream_t stream) {
    (void)in_sizes; (void)n_in; (void)out_size; (void)ws_size;
    const float* x   = (const float*)d_in[0];
    const float* wif = (const float*)d_in[1];
    const float* whf = (const float*)d_in[2];
    const float* bf  = (const float*)d_in[3];
    const float* wir = (const float*)d_in[4];
    const float* whr = (const float*)d_in[5];
    const float* br  = (const float*)d_in[6];
    const float* bw  = (const float*)d_in[7];
    const float* bb  = (const float*)d_in[8];
    const float* g1  = (const float*)d_in[9];  const float* be1 = (const float*)d_in[10];
    const float* g2  = (const float*)d_in[11]; const float* be2 = (const float*)d_in[12];
    const float* g3  = (const float*)d_in[13]; const float* be3 = (const float*)d_in[14];
    const float* g4  = (const float*)d_in[15]; const float* be4 = (const float*)d_in[16];
    const float* g5  = (const float*)d_in[17]; const float* be5 = (const float*)d_in[18];
    const float* w2  = (const float*)d_in[19]; const float* b2  = (const float*)d_in[20];
    const float* w3  = (const float*)d_in[21]; const float* b3  = (const float*)d_in[22];
    const float* w4  = (const float*)d_in[23]; const float* b4  = (const float*)d_in[24];
    const float* w5  = (const float*)d_in[25]; const float* b5  = (const float*)d_in[26];
    const float* fcw = (const float*)d_in[27]; const float* fcb = (const float*)d_in[28];
    float* out = (float*)d_out;
    float* ws  = (float*)d_ws;

    // Workspace layout (floats). xg region is reused by `wave` after the LSTM.
    float* xg_f  = ws;                       //  4,243,456
    float* xg_r  = ws + 4243456;             //  4,243,456
    float* wave  = ws;                       // 12,730,368 (reuses xg region)
    float* X     = ws + 12730368;            //  2,121,728 (dead after wave_kernel)
    float* y2    = ws + 14852096;            //  2,113,536
    float* y3    = ws + 16965632;            //    524,288
    float* y4    = ws + 17489920;            //    261,120
    float* y5    = ws + 17751040;            //    261,120
    float* stats = ws + 18012160;            //      1,536 (BN1 s/s2)
    float* m1 = ws + 18013696; float* r1 = m1 + 768;
    float* m2 = r1 + 768;      float* r2 = m2 + 128;
    float* m3 = r2 + 128;      float* r3 = m3 + 32;
    float* tpart = r3 + 32;                  //      2,048 (tail partials)
    // Folded weights live in the dead X region (X only read by wave_kernel):
    float* w2t  = X;                  // 294,912
    float* b2t  = X + 294912;         //     128
    float* w3t  = X + 295040;         //  20,480
    float* b3t  = X + 315520;         //      32
    float* w4t  = X + 315552;         //   1,536
    float* b4t  = X + 317088;         //      16
    float* bnp3 = X + 317104;         //      64  (BN3 sc|sh for dwt)

    // 1) input projections + zero BN1 stats
    xg_kernel<<<dim3(65, 32), 256, 0, stream>>>(x, wif, bf, wir, br, xg_f, xg_r, stats);
    // 2) bidirectional LSTM recurrence -> X (2-wave structure, LDS weights)
    lstm_kernel<<<dim3(64), 128, 0, stream>>>(xg_f, xg_r, whf, whr, X);
    // 3) wave module -> wave (raw), fused BN1 partial stats
    wave_kernel<<<dim3(3, CCH, B_), 256, 0, stream>>>(X, bw, bb, wave, stats);
    bn1_finalize_kernel<<<dim3(1), 768, 0, stream>>>(stats, m1, r1);
    // 4) fold BN1 into conv2 weights; conv2 on raw wave
    bnfold2_kernel<<<dim3(128), 256, 0, stream>>>(w2, b2, m1, r1, g1, be1, w2t, b2t);
    conv2_kernel<<<dim3(32, 3, 8), 256, 0, stream>>>(wave, w2t, b2t, y2);
    // 5) BN2 stats on raw y2; fold into conv3; conv3
    bn_stats_kernel<<<dim3(128), 256, 0, stream>>>(y2, B_, 128, L2_, m2, r2);
    bnfold3_kernel<<<dim3(32), 256, 0, stream>>>(w3, b3, m2, r2, g2, be2, w3t, b3t);
    conv3_kernel<<<dim3(32, 2, 4), 256, 0, stream>>>(y2, w3t, b3t, y3);
    // 6) BN3 stats on raw y3; fold into conv4 + dwt affine
    bn_stats_kernel<<<dim3(32), 256, 0, stream>>>(y3, B_, 32, L3_, m3, r3);
    bnfold4_kernel<<<dim3(16), 128, 0, stream>>>(w4, b4, m3, r3, g3, be3, w4t, b4t, bnp3);
    // 7) conv4 on raw y3 (folded)
    conv4_kernel<<<dim3(32, 2), 256, 0, stream>>>(y3, w4t, b4t, y4);
    // 8) fused BN3-affine + DWT + conv5
    dwt_conv5_kernel<<<dim3(B_), 512, 0, stream>>>(y3, w5, b5, bnp3, y5);
    // 9) tail: parallel partial sums, then BN4/BN5 + pooling + FC
    tail_partial_kernel<<<dim3(B_), 512, 0, stream>>>(y4, y5, tpart);
    tail_final_kernel<<<dim3(1), 512, 0, stream>>>(tpart, g4, be4, g5, be5, fcw, fcb, out);
}

// Round 8
// 914.599 us; speedup vs baseline: 1.2604x; 1.2604x over previous
//
#include <hip/hip_runtime.h>
#include <math.h>

// Problem constants
#define B_     32
#define F_     64
#define T_     518
#define HID    64
#define GATES  256   // 4*HID
#define CCH    128   // 2*HID lstm output channels
#define NWAVE  6
#define WCH    768   // NWAVE*CCH
#define L2_    516   // T-2   (conv2 out)
#define L3_    512   // L2-4  (conv3 out)
#define L4_    510   // L3-2  (conv4/conv5 out)

typedef float v2f __attribute__((ext_vector_type(2)));

__device__ __forceinline__ float frcp(float x) { return __builtin_amdgcn_rcpf(x); }
__device__ __forceinline__ float fsigmoid(float x) { return frcp(1.f + __expf(-x)); }
__device__ __forceinline__ float ftanh(float x) { return 1.f - 2.f * frcp(1.f + __expf(2.f * x)); }

// ---------------------------------------------------------------------------
// K1: input projections, both dirs. Output layout xg[t][w][r][g2] (coalesced).
// (R0-proven variant.)
__global__ void xg_kernel(const float* __restrict__ x,
                          const float* __restrict__ wif, const float* __restrict__ bf,
                          const float* __restrict__ wir, const float* __restrict__ br,
                          float* __restrict__ xg_f, float* __restrict__ xg_r,
                          float* __restrict__ stats) {
    if (blockIdx.x == 0 && blockIdx.y == 0) {
        for (int i = threadIdx.x; i < 2 * WCH; i += 256) stats[i] = 0.f;
    }
    const int tid = threadIdx.x;
    const int wv  = tid >> 7;
    const int g2  = tid & 1;
    const int r   = (tid >> 1) & 63;
    const int g   = (2 * wv + g2) * 64 + r;       // gate row; store offset == tid
    const int b   = blockIdx.y;
    const int t0  = blockIdx.x * 8;
    float4 wa[16], wb[16];
    const float4* w0 = (const float4*)(wif + g * F_);
    const float4* w1 = (const float4*)(wir + g * F_);
#pragma unroll
    for (int i = 0; i < 16; ++i) { wa[i] = w0[i]; wb[i] = w1[i]; }
    const float bfv = bf[g], brv = br[g];
    for (int tt = 0; tt < 8; ++tt) {
        const int t = t0 + tt;
        if (t >= T_) break;
        const float* xp = x + (size_t)b * F_ * T_ + t;
        float a0 = bfv, a1 = brv;
#pragma unroll
        for (int i = 0; i < 16; ++i) {
            float x0 = xp[(i * 4 + 0) * T_];
            float x1 = xp[(i * 4 + 1) * T_];
            float x2 = xp[(i * 4 + 2) * T_];
            float x3 = xp[(i * 4 + 3) * T_];
            a0 += wa[i].x * x0 + wa[i].y * x1 + wa[i].z * x2 + wa[i].w * x3;
            a1 += wb[i].x * x0 + wb[i].y * x1 + wb[i].z * x2 + wb[i].w * x3;
        }
        const size_t o = ((size_t)b * T_ + t) * GATES + tid;   // coalesced
        xg_f[o] = a0;
        xg_r[o] = a1;
    }
}

// ---------------------------------------------------------------------------
// K2: LSTM recurrence — R0 2-wave structure + software-pipelined weight
// streaming. R7 post-mortem: LDS weights are SLOWER (ds_read_b128 ~85 B/cy
// vs L2 stream ~110 B/cy); R0's 298 µs is MLP-bound (compiler remats loads
// tightly, ~5 outstanding vs 200 cy L2 latency). Fix: stream the 32 weight
// float4s in 4 chunks of 8, issuing chunk i+1's loads before chunk i's
// FMAs. Live set ~90 VGPRs — under the allocator's ~150 threshold, so the
// schedule should survive. FMA order per component identical to R0.
// grid(64), block 128.
__global__ __launch_bounds__(128, 1) void lstm_kernel(
        const float* __restrict__ xgi_f, const float* __restrict__ xgi_r,
        const float* __restrict__ whf, const float* __restrict__ whr,
        float* __restrict__ X) {
    const int dir = blockIdx.x & 1;
    const int b   = blockIdx.x >> 1;
    const float* xg  = (dir ? xgi_r : xgi_f) + (size_t)b * T_ * GATES;
    const float* whh = dir ? whr : whf;
    const int tid = threadIdx.x;
    const int r   = tid & 63;
    const int w   = tid >> 6;            // wave 0: gates i,f ; wave 1: gates g,o

    const float4* __restrict__ pA = (const float4*)(whh + (size_t)((2 * w) * HID + r) * HID);
    const float4* __restrict__ pB = (const float4*)(whh + (size_t)((2 * w + 1) * HID + r) * HID);

    __shared__ __align__(16) float hs[2][HID];        // per-wave private h
    __shared__ __align__(16) float gbuf[2][HID][4];   // double-buffered gates
    hs[w][r] = 0.f;
    float c = 0.f;
    float* Xrow = X + ((size_t)(b * CCH + dir * HID + r)) * T_;

    int t = dir ? (T_ - 1) : 0;
    const int step = dir ? -1 : 1;
    const float2* xg2 = (const float2*)xg;   // index (t*2 + w)*64 + r
    float2 q0 = xg2[((size_t)t * 2 + w) * 64 + r];
    float2 q1 = xg2[((size_t)(t + step) * 2 + w) * 64 + r];
    __syncthreads();

    for (int s = 0; s < T_; ++s) {
        float4 a0 = {q0.x, 0.f, 0.f, 0.f};
        float4 a1 = {q0.y, 0.f, 0.f, 0.f};
        const float4* h4p = (const float4*)hs[w];

        // chunk 0 preload (8 float4 in flight)
        float4 ca0 = pA[0], ca1 = pA[1], ca2 = pA[2], ca3 = pA[3];
        float4 cb0 = pB[0], cb1 = pB[1], cb2 = pB[2], cb3 = pB[3];
#pragma unroll
        for (int ch = 0; ch < 4; ++ch) {
            float4 na0, na1, na2, na3, nb0, nb1, nb2, nb3;
            if (ch < 3) {
                const int o = 4 * (ch + 1);
                na0 = pA[o]; na1 = pA[o + 1]; na2 = pA[o + 2]; na3 = pA[o + 3];
                nb0 = pB[o]; nb1 = pB[o + 1]; nb2 = pB[o + 2]; nb3 = pB[o + 3];
            }
            const float4 h0 = h4p[4 * ch + 0];
            const float4 h1 = h4p[4 * ch + 1];
            const float4 h2 = h4p[4 * ch + 2];
            const float4 h3 = h4p[4 * ch + 3];
            a0.x = fmaf(ca0.x, h0.x, a0.x); a0.y = fmaf(ca0.y, h0.y, a0.y);
            a0.z = fmaf(ca0.z, h0.z, a0.z); a0.w = fmaf(ca0.w, h0.w, a0.w);
            a0.x = fmaf(ca1.x, h1.x, a0.x); a0.y = fmaf(ca1.y, h1.y, a0.y);
            a0.z = fmaf(ca1.z, h1.z, a0.z); a0.w = fmaf(ca1.w, h1.w, a0.w);
            a0.x = fmaf(ca2.x, h2.x, a0.x); a0.y = fmaf(ca2.y, h2.y, a0.y);
            a0.z = fmaf(ca2.z, h2.z, a0.z); a0.w = fmaf(ca2.w, h2.w, a0.w);
            a0.x = fmaf(ca3.x, h3.x, a0.x); a0.y = fmaf(ca3.y, h3.y, a0.y);
            a0.z = fmaf(ca3.z, h3.z, a0.z); a0.w = fmaf(ca3.w, h3.w, a0.w);
            a1.x = fmaf(cb0.x, h0.x, a1.x); a1.y = fmaf(cb0.y, h0.y, a1.y);
            a1.z = fmaf(cb0.z, h0.z, a1.z); a1.w = fmaf(cb0.w, h0.w, a1.w);
            a1.x = fmaf(cb1.x, h1.x, a1.x); a1.y = fmaf(cb1.y, h1.y, a1.y);
            a1.z = fmaf(cb1.z, h1.z, a1.z); a1.w = fmaf(cb1.w, h1.w, a1.w);
            a1.x = fmaf(cb2.x, h2.x, a1.x); a1.y = fmaf(cb2.y, h2.y, a1.y);
            a1.z = fmaf(cb2.z, h2.z, a1.z); a1.w = fmaf(cb2.w, h2.w, a1.w);
            a1.x = fmaf(cb3.x, h3.x, a1.x); a1.y = fmaf(cb3.y, h3.y, a1.y);
            a1.z = fmaf(cb3.z, h3.z, a1.z); a1.w = fmaf(cb3.w, h3.w, a1.w);
            ca0 = na0; ca1 = na1; ca2 = na2; ca3 = na3;
            cb0 = nb0; cb1 = nb1; cb2 = nb2; cb3 = nb3;
        }
        const float gA = (a0.x + a0.y) + (a0.z + a0.w);
        const float gB = (a1.x + a1.y) + (a1.z + a1.w);
        const int buf = s & 1;
        *(float2*)&gbuf[buf][r][2 * w] = make_float2(gA, gB);

        int tp = t + 2 * step;
        tp = tp < 0 ? 0 : (tp >= T_ ? T_ - 1 : tp);
        const float2 qn = xg2[((size_t)tp * 2 + w) * 64 + r];

        asm volatile("s_waitcnt lgkmcnt(0)" ::: "memory");
        __builtin_amdgcn_s_barrier();

        const float4 g4 = *(const float4*)gbuf[buf][r];   // i,f,g,o
        const float si = fsigmoid(g4.x);
        const float sf = fsigmoid(g4.y);
        const float so = fsigmoid(g4.w);
        c = sf * c + si * ftanh(g4.z);
        const float h = so * ftanh(c);

        hs[w][r] = h;
        if (w == 0) Xrow[t] = h;
        q0 = q1; q1 = qn;
        t += step;
    }
}

// ---------------------------------------------------------------------------
// K3: wave module + fused BN1 partial stats. grid(3, 128, 32), block 256
__global__ void wave_kernel(const float* __restrict__ X,
                            const float* __restrict__ bw, const float* __restrict__ bb,
                            float* __restrict__ wave, float* __restrict__ stats) {
    const int b = blockIdx.z, c = blockIdx.y;
    const int t0 = blockIdx.x * 256;
    const int tid = threadIdx.x;
    __shared__ float xs[256 + 14];
    __shared__ float bws[NWAVE][16];
    __shared__ float bbs[NWAVE];
    __shared__ float red[4][12];
    const float* xrow = X + ((size_t)(b * CCH + c)) * T_;
    for (int i = tid; i < 270; i += 256) {
        int tt = t0 - 7 + i;
        xs[i] = (tt >= 0 && tt < T_) ? xrow[tt] : 0.f;
    }
    if (tid < NWAVE * 15) bws[tid / 15][tid % 15] = bw[tid];
    if (tid < NWAVE) bbs[tid] = bb[tid];
    __syncthreads();
    const int t = t0 + tid;
    float ls[NWAVE], lq[NWAVE];
#pragma unroll
    for (int ii = 0; ii < NWAVE; ++ii) { ls[ii] = 0.f; lq[ii] = 0.f; }
    if (t < T_) {
        float win[15];
#pragma unroll
        for (int k = 0; k < 15; ++k) win[k] = xs[tid + k];
        float e[8];
        e[0] = win[7];
#pragma unroll
        for (int m = 1; m < 8; ++m) e[m] = win[7 - m] + win[7 + m];
        const float c0 = 6.28318530717958647692f / 15.f;  // 2*pi/WIDE
#pragma unroll
        for (int ii = 0; ii < NWAVE; ++ii) {
            float sc = bbs[ii];
#pragma unroll
            for (int k = 0; k < 15; ++k) sc += win[k] * bws[ii][k];
            sc = fmaxf(sc, 0.f);
            const float phi = c0 * (float)(ii + 1) * sc;
            float o = e[0];
#pragma unroll
            for (int m = 1; m < 8; ++m) o += e[m] * __cosf(phi * (float)m);
            const float q = (truncf(sc * 15.f) + 1.f) * (2.f / 17.f);
            const float val = o * rsqrtf(q);
            wave[((size_t)(b * WCH + ii * CCH + c)) * T_ + t] = val;
            ls[ii] = val;
            lq[ii] = val * val;
        }
    }
#pragma unroll
    for (int off = 32; off > 0; off >>= 1) {
#pragma unroll
        for (int ii = 0; ii < NWAVE; ++ii) {
            ls[ii] += __shfl_down(ls[ii], off);
            lq[ii] += __shfl_down(lq[ii], off);
        }
    }
    if ((tid & 63) == 0) {
        const int w = tid >> 6;
#pragma unroll
        for (int ii = 0; ii < NWAVE; ++ii) { red[w][ii] = ls[ii]; red[w][6 + ii] = lq[ii]; }
    }
    __syncthreads();
    if (tid < 12) {
        const float a = red[0][tid] + red[1][tid] + red[2][tid] + red[3][tid];
        const int ii = tid % 6;
        const int ch = ii * CCH + c;
        atomicAdd(&stats[(tid >= 6 ? WCH : 0) + ch], a);
    }
}

// Finalize BN1 stats: 1 block, 768 threads
__global__ void bn1_finalize_kernel(const float* __restrict__ stats,
                                    float* __restrict__ mean, float* __restrict__ rstd) {
    const int c = threadIdx.x;
    const float n = (float)(B_ * T_);
    const float m = stats[c] / n;
    const float v = stats[WCH + c] / n - m * m;
    mean[c] = m;
    rstd[c] = rsqrtf(v + 1e-5f);
}

// ---------------------------------------------------------------------------
// Generic training-mode BN statistics: one block per channel
__global__ void bn_stats_kernel(const float* __restrict__ x, int Bn, int C, int L,
                                float* __restrict__ mean, float* __restrict__ rstd) {
    const int c = blockIdx.x;
    const int tid = threadIdx.x;
    float s = 0.f, s2 = 0.f;
    for (int b = 0; b < Bn; ++b) {
        const float* row = x + ((size_t)b * C + c) * L;
        for (int l = tid; l < L; l += 256) { float v = row[l]; s += v; s2 += v * v; }
    }
#pragma unroll
    for (int off = 32; off > 0; off >>= 1) { s += __shfl_down(s, off); s2 += __shfl_down(s2, off); }
    __shared__ float ss[4], ss2[4];
    if ((tid & 63) == 0) { ss[tid >> 6] = s; ss2[tid >> 6] = s2; }
    __syncthreads();
    if (tid == 0) {
        float S = ss[0] + ss[1] + ss[2] + ss[3];
        float S2 = ss2[0] + ss2[1] + ss2[2] + ss2[3];
        float n = (float)(Bn * L);
        float m = S / n;
        float v = S2 / n - m * m;
        mean[c] = m;
        rstd[c] = rsqrtf(v + 1e-5f);
    }
}

// ---------------------------------------------------------------------------
// BN-fold transforms: w'[c,k,o] = w[o,c,k]*sc[c]; b'[o] = b[o] + sum w*sh[c].
// bnfold2: grid(128), block 256 (one block per output channel)
__global__ void bnfold2_kernel(const float* __restrict__ w2, const float* __restrict__ b2,
                               const float* __restrict__ m1, const float* __restrict__ r1,
                               const float* __restrict__ g1, const float* __restrict__ be1,
                               float* __restrict__ w2t, float* __restrict__ b2t) {
    const int o = blockIdx.x, tid = threadIdx.x;
    float part = 0.f;
    for (int idx = tid; idx < WCH * 3; idx += 256) {
        const int c = idx / 3;
        const float sc = r1[c] * g1[c];
        const float sh = be1[c] - m1[c] * sc;
        const float wv = w2[(size_t)o * (WCH * 3) + idx];
        w2t[(size_t)idx * 128 + o] = wv * sc;
        part += wv * sh;
    }
#pragma unroll
    for (int off = 32; off > 0; off >>= 1) part += __shfl_down(part, off);
    __shared__ float red[4];
    if ((tid & 63) == 0) red[tid >> 6] = part;
    __syncthreads();
    if (tid == 0) b2t[o] = b2[o] + red[0] + red[1] + red[2] + red[3];
}

// bnfold3: grid(32), block 256
__global__ void bnfold3_kernel(const float* __restrict__ w3, const float* __restrict__ b3,
                               const float* __restrict__ m2, const float* __restrict__ r2,
                               const float* __restrict__ g2, const float* __restrict__ be2,
                               float* __restrict__ w3t, float* __restrict__ b3t) {
    const int o = blockIdx.x, tid = threadIdx.x;
    float part = 0.f;
    for (int idx = tid; idx < 128 * 5; idx += 256) {
        const int c = idx / 5;
        const float sc = r2[c] * g2[c];
        const float sh = be2[c] - m2[c] * sc;
        const float wv = w3[(size_t)o * 640 + idx];
        w3t[(size_t)idx * 32 + o] = wv * sc;
        part += wv * sh;
    }
#pragma unroll
    for (int off = 32; off > 0; off >>= 1) part += __shfl_down(part, off);
    __shared__ float red[4];
    if ((tid & 63) == 0) red[tid >> 6] = part;
    __syncthreads();
    if (tid == 0) b3t[o] = b3[o] + red[0] + red[1] + red[2] + red[3];
}

// bnfold4: grid(16), block 128. Block 0 also emits BN3 affine (sc,sh) for dwt.
__global__ void bnfold4_kernel(const float* __restrict__ w4, const float* __restrict__ b4,
                               const float* __restrict__ m3, const float* __restrict__ r3,
                               const float* __restrict__ g3, const float* __restrict__ be3,
                               float* __restrict__ w4t, float* __restrict__ b4t,
                               float* __restrict__ bnp3) {
    const int o = blockIdx.x, tid = threadIdx.x;
    float part = 0.f;
    if (tid < 96) {
        const int c = tid / 3;
        const float sc = r3[c] * g3[c];
        const float sh = be3[c] - m3[c] * sc;
        const float wv = w4[(size_t)o * 96 + tid];
        w4t[(size_t)tid * 16 + o] = wv * sc;
        part = wv * sh;
    }
    if (o == 0 && tid >= 96) {
        const int ch = tid - 96;
        const float sc = r3[ch] * g3[ch];
        bnp3[ch] = sc;
        bnp3[32 + ch] = be3[ch] - m3[ch] * sc;
    }
#pragma unroll
    for (int off = 32; off > 0; off >>= 1) part += __shfl_down(part, off);
    __shared__ float red[2];
    if ((tid & 63) == 0) red[tid >> 6] = part;
    __syncthreads();
    if (tid == 0) b4t[o] = b4[o] + red[0] + red[1];
}

// ---------------------------------------------------------------------------
// conv2 (BN1 folded): wave_raw [32,768,518] -> relu -> y2 [32,128,516], k=3.
// v2f accumulators -> v_pk_fma_f32 halves the FMA issue. Weights [c][k][o].
// grid(32 b, 3 t, 8 o).
__global__ __launch_bounds__(256) void conv2_kernel(
        const float* __restrict__ in, const float* __restrict__ wt,
        const float* __restrict__ bt, float* __restrict__ out) {
    const int b  = blockIdx.x;
    const int t  = blockIdx.y * 256 + threadIdx.x;
    const int o0 = blockIdx.z * 16;
    if (t >= L2_) return;
    v2f acc[8];
    const v2f* bt2 = (const v2f*)(bt + o0);
#pragma unroll
    for (int j = 0; j < 8; ++j) acc[j] = bt2[j];
    const float* inb = in + (size_t)b * WCH * T_ + t;
    for (int c = 0; c < WCH; ++c) {
        const float x0 = inb[c * T_], x1 = inb[c * T_ + 1], x2 = inb[c * T_ + 2];
        const v2f vx0 = {x0, x0}, vx1 = {x1, x1}, vx2 = {x2, x2};
        const v2f* wc = (const v2f*)(wt + (size_t)c * 384 + o0);  // k-stride 64 v2f
#pragma unroll
        for (int j = 0; j < 8; ++j)
            acc[j] = __builtin_elementwise_fma(wc[j], vx0,
                     __builtin_elementwise_fma(wc[64 + j], vx1,
                     __builtin_elementwise_fma(wc[128 + j], vx2, acc[j])));
    }
    const size_t ob = ((size_t)b * 128 + o0) * L2_ + t;
#pragma unroll
    for (int j = 0; j < 8; ++j) {
        out[ob + (size_t)(2 * j) * L2_]     = fmaxf(acc[j].x, 0.f);
        out[ob + (size_t)(2 * j + 1) * L2_] = fmaxf(acc[j].y, 0.f);
    }
}

// conv3 (BN2 folded): y2_raw [32,128,516] -> relu -> y3 [32,32,512], k=5.
// grid(32 b, 2 t, 4 o), v2f accumulators, weights [c][k][o].
__global__ __launch_bounds__(256) void conv3_kernel(
        const float* __restrict__ in, const float* __restrict__ wt,
        const float* __restrict__ bt, float* __restrict__ out) {
    const int b  = blockIdx.x;
    const int t  = blockIdx.y * 256 + threadIdx.x;   // < 512 always
    const int o0 = blockIdx.z * 8;
    v2f acc[4];
    const v2f* bt2 = (const v2f*)(bt + o0);
#pragma unroll
    for (int j = 0; j < 4; ++j) acc[j] = bt2[j];
    const float* inb = in + (size_t)b * 128 * L2_ + t;
    for (int c = 0; c < 128; ++c) {
        const float x0 = inb[c * L2_], x1 = inb[c * L2_ + 1], x2 = inb[c * L2_ + 2];
        const float x3 = inb[c * L2_ + 3], x4 = inb[c * L2_ + 4];
        const v2f vx0 = {x0, x0}, vx1 = {x1, x1}, vx2 = {x2, x2}, vx3 = {x3, x3}, vx4 = {x4, x4};
        const v2f* wc = (const v2f*)(wt + (size_t)c * 160 + o0);  // k-stride 16 v2f
#pragma unroll
        for (int j = 0; j < 4; ++j)
            acc[j] = __builtin_elementwise_fma(wc[j], vx0,
                     __builtin_elementwise_fma(wc[16 + j], vx1,
                     __builtin_elementwise_fma(wc[32 + j], vx2,
                     __builtin_elementwise_fma(wc[48 + j], vx3,
                     __builtin_elementwise_fma(wc[64 + j], vx4, acc[j])))));
    }
    const size_t ob = ((size_t)b * 32 + o0) * L3_ + t;
#pragma unroll
    for (int j = 0; j < 4; ++j) {
        out[ob + (size_t)(2 * j) * L3_]     = fmaxf(acc[j].x, 0.f);
        out[ob + (size_t)(2 * j + 1) * L3_] = fmaxf(acc[j].y, 0.f);
    }
}

// conv4 (BN3 folded): y3_raw [32,32,512] -> relu -> y4 [32,16,510], k=3.
// grid(32 b, 2 t), block 256, v2f accumulators.
__global__ __launch_bounds__(256) void conv4_kernel(
        const float* __restrict__ in, const float* __restrict__ wt,
        const float* __restrict__ bt, float* __restrict__ out) {
    const int b = blockIdx.x;
    const int t = blockIdx.y * 256 + threadIdx.x;
    if (t >= L4_) return;
    v2f acc[8];
    const v2f* bt2 = (const v2f*)bt;
#pragma unroll
    for (int j = 0; j < 8; ++j) acc[j] = bt2[j];
    const float* inb = in + (size_t)b * 32 * L3_ + t;
    for (int c = 0; c < 32; ++c) {
        const float x0 = inb[c * L3_], x1 = inb[c * L3_ + 1], x2 = inb[c * L3_ + 2];
        const v2f vx0 = {x0, x0}, vx1 = {x1, x1}, vx2 = {x2, x2};
        const v2f* wc = (const v2f*)(wt + (size_t)c * 48);        // k-stride 8 v2f
#pragma unroll
        for (int j = 0; j < 8; ++j)
            acc[j] = __builtin_elementwise_fma(wc[j], vx0,
                     __builtin_elementwise_fma(wc[8 + j], vx1,
                     __builtin_elementwise_fma(wc[16 + j], vx2, acc[j])));
    }
    const size_t ob = ((size_t)b * 16) * L4_ + t;
#pragma unroll
    for (int j = 0; j < 8; ++j) {
        out[ob + (size_t)(2 * j) * L4_]     = fmaxf(acc[j].x, 0.f);
        out[ob + (size_t)(2 * j + 1) * L4_] = fmaxf(acc[j].y, 0.f);
    }
}

// Fused BN3(inline) + DWT bands + conv5 + relu -> y5 [32,16,510]. grid(32), block 512
__global__ __launch_bounds__(512) void dwt_conv5_kernel(const float* __restrict__ y3,
                                                        const float* __restrict__ w5,
                                                        const float* __restrict__ b5,
                                                        const float* __restrict__ bnp3,
                                                        float* __restrict__ y5) {
    const int b = blockIdx.x, l = threadIdx.x;  // l in [0,512)
    __shared__ float cm[L3_];
    __shared__ float bands[5][L3_];
    __shared__ float w5s[240];
    __shared__ float b5s[16];
    __shared__ float sc3s[32], sh3s[32];
    if (l < 240) w5s[l] = w5[l];
    if (l < 16) b5s[l] = b5[l];
    if (l >= 256 && l < 288) sc3s[l - 256] = bnp3[l - 256];
    if (l >= 288 && l < 320) sh3s[l - 288] = bnp3[32 + (l - 288)];
    __syncthreads();
    float s = 0.f, shs = 0.f;
    for (int ch = 0; ch < 32; ++ch) {
        s = fmaf(y3[((size_t)b * 32 + ch) * L3_ + l], sc3s[ch], s);
        shs += sh3s[ch];
    }
    cm[l] = (s + shs) * (1.f / 32.f);
    __syncthreads();
    const float s1 = 0.70710678118654752440f;
    const float s2c = 0.5f;
    const float s3 = 0.35355339059327378f;
    const float s4 = 0.25f;
    const int b16 = l & ~15, b8 = l & ~7, b4v = l & ~3, b2v = l & ~1;
    float sa = 0.f, sb = 0.f;
#pragma unroll
    for (int i = 0; i < 8; ++i) { sa += cm[b16 + i]; sb += cm[b16 + 8 + i]; }
    bands[0][l] = (sa + sb) * s4;
    bands[1][l] = (sa - sb) * s4;
    float ta = 0.f, tb = 0.f;
#pragma unroll
    for (int i = 0; i < 4; ++i) { ta += cm[b8 + i]; tb += cm[b8 + 4 + i]; }
    bands[2][l] = (ta - tb) * s3;
    bands[3][l] = (cm[b4v] + cm[b4v + 1] - cm[b4v + 2] - cm[b4v + 3]) * s2c;
    bands[4][l] = (cm[b2v] - cm[b2v + 1]) * s1;
    __syncthreads();
    if (l < L4_) {
        float in3[5][3];
#pragma unroll
        for (int c = 0; c < 5; ++c) {
            in3[c][0] = bands[c][l]; in3[c][1] = bands[c][l + 1]; in3[c][2] = bands[c][l + 2];
        }
#pragma unroll
        for (int o = 0; o < 16; ++o) {
            float acc = b5s[o];
#pragma unroll
            for (int c = 0; c < 5; ++c) {
                const float* wp = &w5s[(o * 5 + c) * 3];
                acc += in3[c][0] * wp[0] + in3[c][1] * wp[1] + in3[c][2] * wp[2];
            }
            y5[((size_t)b * 16 + o) * L4_ + l] = fmaxf(acc, 0.f);
        }
    }
}

// Tail stage A: per-(b,ch) sums/sumsq of y4 and y5. grid(32), block 512.
__global__ __launch_bounds__(512) void tail_partial_kernel(
        const float* __restrict__ y4, const float* __restrict__ y5,
        float* __restrict__ part) {
    const int b = blockIdx.x;
    const int p = threadIdx.x;
    const int ch = p >> 5;             // 16 channels
    const int sl = p & 31;             // 32 lanes per channel
    const float2* p4 = (const float2*)(y4 + ((size_t)(b * 16 + ch)) * L4_);
    const float2* p5 = (const float2*)(y5 + ((size_t)(b * 16 + ch)) * L4_);
    float s4 = 0.f, q4 = 0.f, s5 = 0.f, q5 = 0.f;
    for (int i = sl; i < L4_ / 2; i += 32) {
        float2 a = p4[i], e = p5[i];
        s4 += a.x + a.y;  q4 += a.x * a.x + a.y * a.y;
        s5 += e.x + e.y;  q5 += e.x * e.x + e.y * e.y;
    }
#pragma unroll
    for (int off = 16; off > 0; off >>= 1) {
        s4 += __shfl_down(s4, off, 32); q4 += __shfl_down(q4, off, 32);
        s5 += __shfl_down(s5, off, 32); q5 += __shfl_down(q5, off, 32);
    }
    if (sl == 0) {
        float4* o = (float4*)part;
        o[b * 16 + ch] = make_float4(s4, q4, s5, q5);
    }
}

// Tail stage B: BN4/BN5 stats + pooling(+affine) + FC. grid(1), block 512.
__global__ __launch_bounds__(512) void tail_final_kernel(
        const float* __restrict__ part,
        const float* __restrict__ g4, const float* __restrict__ be4,
        const float* __restrict__ g5, const float* __restrict__ be5,
        const float* __restrict__ fcw, const float* __restrict__ fcb,
        float* __restrict__ out) {
    const int p = threadIdx.x;           // 0..511
    const int b = p >> 4, ch = p & 15;
    const float4 v = ((const float4*)part)[b * 16 + ch];  // s4,q4,s5,q5
    __shared__ float S4[512], Q4[512], S5[512], Q5[512];
    __shared__ float M4[16], R4[16], M5[16], R5[16];
    __shared__ float pool[B_][16];
    S4[p] = v.x; Q4[p] = v.y; S5[p] = v.z; Q5[p] = v.w;
    __syncthreads();
    if (p < 16) {
        float ts = 0.f, tq = 0.f, us = 0.f, uq = 0.f;
        for (int bb = 0; bb < B_; ++bb) {
            ts += S4[bb * 16 + p]; tq += Q4[bb * 16 + p];
            us += S5[bb * 16 + p]; uq += Q5[bb * 16 + p];
        }
        const float n = (float)(B_ * L4_);
        float m = ts / n; M4[p] = m; R4[p] = rsqrtf(tq / n - m * m + 1e-5f);
        m = us / n;       M5[p] = m; R5[p] = rsqrtf(uq / n - m * m + 1e-5f);
    }
    __syncthreads();
    {
        const float mm4 = v.x / (float)L4_, mm5 = v.z / (float)L4_;
        const float v4 = (mm4 - M4[ch]) * R4[ch] * g4[ch] + be4[ch];
        const float v5 = (mm5 - M5[ch]) * R5[ch] * g5[ch] + be5[ch];
        pool[b][ch] = 0.5f * (v4 + v5);
    }
    __syncthreads();
    if (p < B_ * 10) {
        const int bb = p / 10, row = p - bb * 10;
        float a = fcb[row];
#pragma unroll
        for (int c = 0; c < 16; ++c) a += pool[bb][c] * fcw[row * 16 + c];
        out[bb * 10 + row] = a;
    }
}

// ---------------------------------------------------------------------------
extern "C" void kernel_launch(void* const* d_in, const int* in_sizes, int n_in,
                              void* d_out, int out_size, void* d_ws, size_t ws_size,
                              hipStream_t stream) {
    (void)in_sizes; (void)n_in; (void)out_size; (void)ws_size;
    const float* x   = (const float*)d_in[0];
    const float* wif = (const float*)d_in[1];
    const float* whf = (const float*)d_in[2];
    const float* bf  = (const float*)d_in[3];
    const float* wir = (const float*)d_in[4];
    const float* whr = (const float*)d_in[5];
    const float* br  = (const float*)d_in[6];
    const float* bw  = (const float*)d_in[7];
    const float* bb  = (const float*)d_in[8];
    const float* g1  = (const float*)d_in[9];  const float* be1 = (const float*)d_in[10];
    const float* g2  = (const float*)d_in[11]; const float* be2 = (const float*)d_in[12];
    const float* g3  = (const float*)d_in[13]; const float* be3 = (const float*)d_in[14];
    const float* g4  = (const float*)d_in[15]; const float* be4 = (const float*)d_in[16];
    const float* g5  = (const float*)d_in[17]; const float* be5 = (const float*)d_in[18];
    const float* w2  = (const float*)d_in[19]; const float* b2  = (const float*)d_in[20];
    const float* w3  = (const float*)d_in[21]; const float* b3  = (const float*)d_in[22];
    const float* w4  = (const float*)d_in[23]; const float* b4  = (const float*)d_in[24];
    const float* w5  = (const float*)d_in[25]; const float* b5  = (const float*)d_in[26];
    const float* fcw = (const float*)d_in[27]; const float* fcb = (const float*)d_in[28];
    float* out = (float*)d_out;
    float* ws  = (float*)d_ws;

    // Workspace layout (floats). xg region is reused by `wave` after the LSTM.
    float* xg_f  = ws;                       //  4,243,456
    float* xg_r  = ws + 4243456;             //  4,243,456
    float* wave  = ws;                       // 12,730,368 (reuses xg region)
    float* X     = ws + 12730368;            //  2,121,728 (dead after wave_kernel)
    float* y2    = ws + 14852096;            //  2,113,536
    float* y3    = ws + 16965632;            //    524,288
    float* y4    = ws + 17489920;            //    261,120
    float* y5    = ws + 17751040;            //    261,120
    float* stats = ws + 18012160;            //      1,536 (BN1 s/s2)
    float* m1 = ws + 18013696; float* r1 = m1 + 768;
    float* m2 = r1 + 768;      float* r2 = m2 + 128;
    float* m3 = r2 + 128;      float* r3 = m3 + 32;
    float* tpart = r3 + 32;                  //      2,048 (tail partials)
    // Folded weights live in the dead X region (X only read by wave_kernel):
    float* w2t  = X;                  // 294,912
    float* b2t  = X + 294912;         //     128
    float* w3t  = X + 295040;         //  20,480
    float* b3t  = X + 315520;         //      32
    float* w4t  = X + 315552;         //   1,536
    float* b4t  = X + 317088;         //      16
    float* bnp3 = X + 317104;         //      64  (BN3 sc|sh for dwt)

    // 1) input projections + zero BN1 stats
    xg_kernel<<<dim3(65, 32), 256, 0, stream>>>(x, wif, bf, wir, br, xg_f, xg_r, stats);
    // 2) bidirectional LSTM recurrence -> X (2-wave, pipelined weight stream)
    lstm_kernel<<<dim3(64), 128, 0, stream>>>(xg_f, xg_r, whf, whr, X);
    // 3) wave module -> wave (raw), fused BN1 partial stats
    wave_kernel<<<dim3(3, CCH, B_), 256, 0, stream>>>(X, bw, bb, wave, stats);
    bn1_finalize_kernel<<<dim3(1), 768, 0, stream>>>(stats, m1, r1);
    // 4) fold BN1 into conv2 weights; conv2 on raw wave
    bnfold2_kernel<<<dim3(128), 256, 0, stream>>>(w2, b2, m1, r1, g1, be1, w2t, b2t);
    conv2_kernel<<<dim3(32, 3, 8), 256, 0, stream>>>(wave, w2t, b2t, y2);
    // 5) BN2 stats on raw y2; fold into conv3; conv3
    bn_stats_kernel<<<dim3(128), 256, 0, stream>>>(y2, B_, 128, L2_, m2, r2);
    bnfold3_kernel<<<dim3(32), 256, 0, stream>>>(w3, b3, m2, r2, g2, be2, w3t, b3t);
    conv3_kernel<<<dim3(32, 2, 4), 256, 0, stream>>>(y2, w3t, b3t, y3);
    // 6) BN3 stats on raw y3; fold into conv4 + dwt affine
    bn_stats_kernel<<<dim3(32), 256, 0, stream>>>(y3, B_, 32, L3_, m3, r3);
    bnfold4_kernel<<<dim3(16), 128, 0, stream>>>(w4, b4, m3, r3, g3, be3, w4t, b4t, bnp3);
    // 7) conv4 on raw y3 (folded)
    conv4_kernel<<<dim3(32, 2), 256, 0, stream>>>(y3, w4t, b4t, y4);
    // 8) fused BN3-affine + DWT + conv5
    dwt_conv5_kernel<<<dim3(B_), 512, 0, stream>>>(y3, w5, b5, bnp3, y5);
    // 9) tail: parallel partial sums, then BN4/BN5 + pooling + FC
    tail_partial_kernel<<<dim3(B_), 512, 0, stream>>>(y4, y5, tpart);
    tail_final_kernel<<<dim3(1), 512, 0, stream>>>(tpart, g4, be4, g5, be5, fcw, fcb, out);
}

// Round 9
// 881.810 us; speedup vs baseline: 1.3073x; 1.0372x over previous
//
#include <hip/hip_runtime.h>
#include <math.h>

// Problem constants
#define B_     32
#define F_     64
#define T_     518
#define HID    64
#define GATES  256   // 4*HID
#define CCH    128   // 2*HID lstm output channels
#define NWAVE  6
#define WCH    768   // NWAVE*CCH
#define L2_    516   // T-2   (conv2 out)
#define L3_    512   // L2-4  (conv3 out)
#define L4_    510   // L3-2  (conv4/conv5 out)

typedef float v2f __attribute__((ext_vector_type(2)));

__device__ __forceinline__ float frcp(float x) { return __builtin_amdgcn_rcpf(x); }
__device__ __forceinline__ float fsigmoid(float x) { return frcp(1.f + __expf(-x)); }
__device__ __forceinline__ float ftanh(float x) { return 1.f - 2.f * frcp(1.f + __expf(2.f * x)); }

// ---------------------------------------------------------------------------
// K1: input projections, both dirs. Output layout xg[t][w][r][g2] (coalesced).
// Also zeroes BN1 stats (1536) and BN2/BN3 raw stats (320).
__global__ void xg_kernel(const float* __restrict__ x,
                          const float* __restrict__ wif, const float* __restrict__ bf,
                          const float* __restrict__ wir, const float* __restrict__ br,
                          float* __restrict__ xg_f, float* __restrict__ xg_r,
                          float* __restrict__ stats, float* __restrict__ stats23) {
    if (blockIdx.x == 0 && blockIdx.y == 0) {
        for (int i = threadIdx.x; i < 2 * WCH; i += 256) stats[i] = 0.f;
        if (threadIdx.x < 320) stats23[threadIdx.x] = 0.f;   // 256 BN2 + 64 BN3
    }
    const int tid = threadIdx.x;
    const int wv  = tid >> 7;
    const int g2  = tid & 1;
    const int r   = (tid >> 1) & 63;
    const int g   = (2 * wv + g2) * 64 + r;       // gate row; store offset == tid
    const int b   = blockIdx.y;
    const int t0  = blockIdx.x * 8;
    float4 wa[16], wb[16];
    const float4* w0 = (const float4*)(wif + g * F_);
    const float4* w1 = (const float4*)(wir + g * F_);
#pragma unroll
    for (int i = 0; i < 16; ++i) { wa[i] = w0[i]; wb[i] = w1[i]; }
    const float bfv = bf[g], brv = br[g];
    for (int tt = 0; tt < 8; ++tt) {
        const int t = t0 + tt;
        if (t >= T_) break;
        const float* xp = x + (size_t)b * F_ * T_ + t;
        float a0 = bfv, a1 = brv;
#pragma unroll
        for (int i = 0; i < 16; ++i) {
            float x0 = xp[(i * 4 + 0) * T_];
            float x1 = xp[(i * 4 + 1) * T_];
            float x2 = xp[(i * 4 + 2) * T_];
            float x3 = xp[(i * 4 + 3) * T_];
            a0 += wa[i].x * x0 + wa[i].y * x1 + wa[i].z * x2 + wa[i].w * x3;
            a1 += wb[i].x * x0 + wb[i].y * x1 + wb[i].z * x2 + wb[i].w * x3;
        }
        const size_t o = ((size_t)b * T_ + t) * GATES + tid;   // coalesced
        xg_f[o] = a0;
        xg_r[o] = a1;
    }
}

// ---------------------------------------------------------------------------
// K2: LSTM recurrence — R0 2-wave structure (proven floor: 427ns/step of
// per-CU weight-byte traffic + ~143ns serial tail; 8 structural variants
// all >= this). FROZEN. grid(64), block 128.
__global__ __launch_bounds__(128, 1) void lstm_kernel(
        const float* __restrict__ xgi_f, const float* __restrict__ xgi_r,
        const float* __restrict__ whf, const float* __restrict__ whr,
        float* __restrict__ X) {
    const int dir = blockIdx.x & 1;
    const int b   = blockIdx.x >> 1;
    const float* xg  = (dir ? xgi_r : xgi_f) + (size_t)b * T_ * GATES;
    const float* whh = dir ? whr : whf;
    const int tid = threadIdx.x;
    const int r   = tid & 63;
    const int w   = tid >> 6;            // wave 0: gates i,f ; wave 1: gates g,o

    float4 wA[16], wB[16];
    {
        const float4* pA = (const float4*)(whh + (size_t)((2 * w) * HID + r) * HID);
        const float4* pB = (const float4*)(whh + (size_t)((2 * w + 1) * HID + r) * HID);
#pragma unroll
        for (int i = 0; i < 16; ++i) { wA[i] = pA[i]; wB[i] = pB[i]; }
    }

    __shared__ __align__(16) float hs[2][HID];        // per-wave private h
    __shared__ __align__(16) float gbuf[2][HID][4];   // double-buffered gates
    hs[w][r] = 0.f;
    float c = 0.f;
    float* Xrow = X + ((size_t)(b * CCH + dir * HID + r)) * T_;

    int t = dir ? (T_ - 1) : 0;
    const int step = dir ? -1 : 1;
    const float2* xg2 = (const float2*)xg;   // index (t*2 + w)*64 + r
    float2 q0 = xg2[((size_t)t * 2 + w) * 64 + r];
    float2 q1 = xg2[((size_t)(t + step) * 2 + w) * 64 + r];

    for (int s = 0; s < T_; ++s) {
        float4 a0 = {q0.x, 0.f, 0.f, 0.f};
        float4 a1 = {q0.y, 0.f, 0.f, 0.f};
        const float4* h4p = (const float4*)hs[w];
#pragma unroll
        for (int i = 0; i < 16; ++i) {
            const float4 h4 = h4p[i];
            a0.x = fmaf(wA[i].x, h4.x, a0.x); a0.y = fmaf(wA[i].y, h4.y, a0.y);
            a0.z = fmaf(wA[i].z, h4.z, a0.z); a0.w = fmaf(wA[i].w, h4.w, a0.w);
            a1.x = fmaf(wB[i].x, h4.x, a1.x); a1.y = fmaf(wB[i].y, h4.y, a1.y);
            a1.z = fmaf(wB[i].z, h4.z, a1.z); a1.w = fmaf(wB[i].w, h4.w, a1.w);
        }
        const float gA = (a0.x + a0.y) + (a0.z + a0.w);
        const float gB = (a1.x + a1.y) + (a1.z + a1.w);
        const int buf = s & 1;
        *(float2*)&gbuf[buf][r][2 * w] = make_float2(gA, gB);

        int tp = t + 2 * step;
        tp = tp < 0 ? 0 : (tp >= T_ ? T_ - 1 : tp);
        const float2 qn = xg2[((size_t)tp * 2 + w) * 64 + r];

        asm volatile("s_waitcnt lgkmcnt(0)" ::: "memory");
        __builtin_amdgcn_s_barrier();

        const float4 g4 = *(const float4*)gbuf[buf][r];   // i,f,g,o
        const float si = fsigmoid(g4.x);
        const float sf = fsigmoid(g4.y);
        const float so = fsigmoid(g4.w);
        c = sf * c + si * ftanh(g4.z);
        const float h = so * ftanh(c);

        hs[w][r] = h;
        if (w == 0) Xrow[t] = h;
        q0 = q1; q1 = qn;
        t += step;
    }
}

// ---------------------------------------------------------------------------
// K3: wave module + fused BN1 partial stats. grid(3, 128, 32), block 256
__global__ void wave_kernel(const float* __restrict__ X,
                            const float* __restrict__ bw, const float* __restrict__ bb,
                            float* __restrict__ wave, float* __restrict__ stats) {
    const int b = blockIdx.z, c = blockIdx.y;
    const int t0 = blockIdx.x * 256;
    const int tid = threadIdx.x;
    __shared__ float xs[256 + 14];
    __shared__ float bws[NWAVE][16];
    __shared__ float bbs[NWAVE];
    __shared__ float red[4][12];
    const float* xrow = X + ((size_t)(b * CCH + c)) * T_;
    for (int i = tid; i < 270; i += 256) {
        int tt = t0 - 7 + i;
        xs[i] = (tt >= 0 && tt < T_) ? xrow[tt] : 0.f;
    }
    if (tid < NWAVE * 15) bws[tid / 15][tid % 15] = bw[tid];
    if (tid < NWAVE) bbs[tid] = bb[tid];
    __syncthreads();
    const int t = t0 + tid;
    float ls[NWAVE], lq[NWAVE];
#pragma unroll
    for (int ii = 0; ii < NWAVE; ++ii) { ls[ii] = 0.f; lq[ii] = 0.f; }
    if (t < T_) {
        float win[15];
#pragma unroll
        for (int k = 0; k < 15; ++k) win[k] = xs[tid + k];
        float e[8];
        e[0] = win[7];
#pragma unroll
        for (int m = 1; m < 8; ++m) e[m] = win[7 - m] + win[7 + m];
        const float c0 = 6.28318530717958647692f / 15.f;  // 2*pi/WIDE
#pragma unroll
        for (int ii = 0; ii < NWAVE; ++ii) {
            float sc = bbs[ii];
#pragma unroll
            for (int k = 0; k < 15; ++k) sc += win[k] * bws[ii][k];
            sc = fmaxf(sc, 0.f);
            const float phi = c0 * (float)(ii + 1) * sc;
            float o = e[0];
#pragma unroll
            for (int m = 1; m < 8; ++m) o += e[m] * __cosf(phi * (float)m);
            const float q = (truncf(sc * 15.f) + 1.f) * (2.f / 17.f);
            const float val = o * rsqrtf(q);
            wave[((size_t)(b * WCH + ii * CCH + c)) * T_ + t] = val;
            ls[ii] = val;
            lq[ii] = val * val;
        }
    }
#pragma unroll
    for (int off = 32; off > 0; off >>= 1) {
#pragma unroll
        for (int ii = 0; ii < NWAVE; ++ii) {
            ls[ii] += __shfl_down(ls[ii], off);
            lq[ii] += __shfl_down(lq[ii], off);
        }
    }
    if ((tid & 63) == 0) {
        const int w = tid >> 6;
#pragma unroll
        for (int ii = 0; ii < NWAVE; ++ii) { red[w][ii] = ls[ii]; red[w][6 + ii] = lq[ii]; }
    }
    __syncthreads();
    if (tid < 12) {
        const float a = red[0][tid] + red[1][tid] + red[2][tid] + red[3][tid];
        const int ii = tid % 6;
        const int ch = ii * CCH + c;
        atomicAdd(&stats[(tid >= 6 ? WCH : 0) + ch], a);
    }
}

// Finalize BN1 stats: 1 block, 768 threads
__global__ void bn1_finalize_kernel(const float* __restrict__ stats,
                                    float* __restrict__ mean, float* __restrict__ rstd) {
    const int c = threadIdx.x;
    const float n = (float)(B_ * T_);
    const float m = stats[c] / n;
    const float v = stats[WCH + c] / n - m * m;
    mean[c] = m;
    rstd[c] = rsqrtf(v + 1e-5f);
}

// ---------------------------------------------------------------------------
// bnfold2: grid(128), block 256 (one block per output channel)
__global__ void bnfold2_kernel(const float* __restrict__ w2, const float* __restrict__ b2,
                               const float* __restrict__ m1, const float* __restrict__ r1,
                               const float* __restrict__ g1, const float* __restrict__ be1,
                               float* __restrict__ w2t, float* __restrict__ b2t) {
    const int o = blockIdx.x, tid = threadIdx.x;
    float part = 0.f;
    for (int idx = tid; idx < WCH * 3; idx += 256) {
        const int c = idx / 3;
        const float sc = r1[c] * g1[c];
        const float sh = be1[c] - m1[c] * sc;
        const float wv = w2[(size_t)o * (WCH * 3) + idx];
        w2t[(size_t)idx * 128 + o] = wv * sc;
        part += wv * sh;
    }
#pragma unroll
    for (int off = 32; off > 0; off >>= 1) part += __shfl_down(part, off);
    __shared__ float red[4];
    if ((tid & 63) == 0) red[tid >> 6] = part;
    __syncthreads();
    if (tid == 0) b2t[o] = b2[o] + red[0] + red[1] + red[2] + red[3];
}

// bnfold3 (BN2 finalize inline from raw stats2): grid(32), block 256
__global__ void bnfold3_kernel(const float* __restrict__ w3, const float* __restrict__ b3,
                               const float* __restrict__ stats2,
                               const float* __restrict__ g2, const float* __restrict__ be2,
                               float* __restrict__ w3t, float* __restrict__ b3t) {
    const int o = blockIdx.x, tid = threadIdx.x;
    __shared__ float sc2s[128], sh2s[128];
    if (tid < 128) {
        const float n = (float)(B_ * L2_);
        const float m = stats2[tid] / n;
        const float v = stats2[128 + tid] / n - m * m;
        const float sc = rsqrtf(v + 1e-5f) * g2[tid];
        sc2s[tid] = sc;
        sh2s[tid] = be2[tid] - m * sc;
    }
    __syncthreads();
    float part = 0.f;
    for (int idx = tid; idx < 128 * 5; idx += 256) {
        const int c = idx / 5;
        const float wv = w3[(size_t)o * 640 + idx];
        w3t[(size_t)idx * 32 + o] = wv * sc2s[c];
        part += wv * sh2s[c];
    }
#pragma unroll
    for (int off = 32; off > 0; off >>= 1) part += __shfl_down(part, off);
    __shared__ float red[4];
    if ((tid & 63) == 0) red[tid >> 6] = part;
    __syncthreads();
    if (tid == 0) b3t[o] = b3[o] + red[0] + red[1] + red[2] + red[3];
}

// bnfold4 (BN3 finalize inline from raw stats3): grid(16), block 128
__global__ void bnfold4_kernel(const float* __restrict__ w4, const float* __restrict__ b4,
                               const float* __restrict__ stats3,
                               const float* __restrict__ g3, const float* __restrict__ be3,
                               float* __restrict__ w4t, float* __restrict__ b4t) {
    const int o = blockIdx.x, tid = threadIdx.x;
    __shared__ float sc3s[32], sh3s[32];
    if (tid < 32) {
        const float n = (float)(B_ * L3_);
        const float m = stats3[tid] / n;
        const float v = stats3[32 + tid] / n - m * m;
        const float sc = rsqrtf(v + 1e-5f) * g3[tid];
        sc3s[tid] = sc;
        sh3s[tid] = be3[tid] - m * sc;
    }
    __syncthreads();
    float part = 0.f;
    if (tid < 96) {
        const int c = tid / 3;
        const float wv = w4[(size_t)o * 96 + tid];
        w4t[(size_t)tid * 16 + o] = wv * sc3s[c];
        part = wv * sh3s[c];
    }
#pragma unroll
    for (int off = 32; off > 0; off >>= 1) part += __shfl_down(part, off);
    __shared__ float red[2];
    if ((tid & 63) == 0) red[tid >> 6] = part;
    __syncthreads();
    if (tid == 0) b4t[o] = b4[o] + red[0] + red[1];
}

// ---------------------------------------------------------------------------
// conv2 (BN1 folded) + fused BN2 partial stats: grid(32 b, 3 t, 8 o), block 256
__global__ __launch_bounds__(256) void conv2_kernel(
        const float* __restrict__ in, const float* __restrict__ wt,
        const float* __restrict__ bt, float* __restrict__ out,
        float* __restrict__ stats2) {
    const int b  = blockIdx.x;
    const int tid = threadIdx.x;
    const int t  = blockIdx.y * 256 + tid;
    const int o0 = blockIdx.z * 16;
    float rv[16], qv[16];
#pragma unroll
    for (int j = 0; j < 16; ++j) rv[j] = 0.f;
    if (t < L2_) {
        v2f acc[8];
        const v2f* bt2 = (const v2f*)(bt + o0);
#pragma unroll
        for (int j = 0; j < 8; ++j) acc[j] = bt2[j];
        const float* inb = in + (size_t)b * WCH * T_ + t;
        for (int c = 0; c < WCH; ++c) {
            const float x0 = inb[c * T_], x1 = inb[c * T_ + 1], x2 = inb[c * T_ + 2];
            const v2f vx0 = {x0, x0}, vx1 = {x1, x1}, vx2 = {x2, x2};
            const v2f* wc = (const v2f*)(wt + (size_t)c * 384 + o0);  // k-stride 64 v2f
#pragma unroll
            for (int j = 0; j < 8; ++j)
                acc[j] = __builtin_elementwise_fma(wc[j], vx0,
                         __builtin_elementwise_fma(wc[64 + j], vx1,
                         __builtin_elementwise_fma(wc[128 + j], vx2, acc[j])));
        }
        const size_t ob = ((size_t)b * 128 + o0) * L2_ + t;
#pragma unroll
        for (int j = 0; j < 8; ++j) {
            rv[2 * j]     = fmaxf(acc[j].x, 0.f);
            rv[2 * j + 1] = fmaxf(acc[j].y, 0.f);
            out[ob + (size_t)(2 * j) * L2_]     = rv[2 * j];
            out[ob + (size_t)(2 * j + 1) * L2_] = rv[2 * j + 1];
        }
    }
#pragma unroll
    for (int j = 0; j < 16; ++j) qv[j] = rv[j] * rv[j];
#pragma unroll
    for (int off = 32; off > 0; off >>= 1) {
#pragma unroll
        for (int j = 0; j < 16; ++j) {
            rv[j] += __shfl_down(rv[j], off);
            qv[j] += __shfl_down(qv[j], off);
        }
    }
    __shared__ float red2[4][32];
    if ((tid & 63) == 0) {
        const int wv = tid >> 6;
#pragma unroll
        for (int j = 0; j < 16; ++j) { red2[wv][j] = rv[j]; red2[wv][16 + j] = qv[j]; }
    }
    __syncthreads();
    if (tid < 32) {
        const float a = red2[0][tid] + red2[1][tid] + red2[2][tid] + red2[3][tid];
        atomicAdd(&stats2[(tid >= 16 ? 128 : 0) + o0 + (tid & 15)], a);
    }
}

// conv3 (BN2 folded) + fused BN3 partial stats: grid(32 b, 2 t, 4 o), block 256
__global__ __launch_bounds__(256) void conv3_kernel(
        const float* __restrict__ in, const float* __restrict__ wt,
        const float* __restrict__ bt, float* __restrict__ out,
        float* __restrict__ stats3) {
    const int b  = blockIdx.x;
    const int tid = threadIdx.x;
    const int t  = blockIdx.y * 256 + tid;   // < 512 always
    const int o0 = blockIdx.z * 8;
    v2f acc[4];
    const v2f* bt2 = (const v2f*)(bt + o0);
#pragma unroll
    for (int j = 0; j < 4; ++j) acc[j] = bt2[j];
    const float* inb = in + (size_t)b * 128 * L2_ + t;
    for (int c = 0; c < 128; ++c) {
        const float x0 = inb[c * L2_], x1 = inb[c * L2_ + 1], x2 = inb[c * L2_ + 2];
        const float x3 = inb[c * L2_ + 3], x4 = inb[c * L2_ + 4];
        const v2f vx0 = {x0, x0}, vx1 = {x1, x1}, vx2 = {x2, x2}, vx3 = {x3, x3}, vx4 = {x4, x4};
        const v2f* wc = (const v2f*)(wt + (size_t)c * 160 + o0);  // k-stride 16 v2f
#pragma unroll
        for (int j = 0; j < 4; ++j)
            acc[j] = __builtin_elementwise_fma(wc[j], vx0,
                     __builtin_elementwise_fma(wc[16 + j], vx1,
                     __builtin_elementwise_fma(wc[32 + j], vx2,
                     __builtin_elementwise_fma(wc[48 + j], vx3,
                     __builtin_elementwise_fma(wc[64 + j], vx4, acc[j])))));
    }
    const size_t ob = ((size_t)b * 32 + o0) * L3_ + t;
    float rv[8], qv[8];
#pragma unroll
    for (int j = 0; j < 4; ++j) {
        rv[2 * j]     = fmaxf(acc[j].x, 0.f);
        rv[2 * j + 1] = fmaxf(acc[j].y, 0.f);
        out[ob + (size_t)(2 * j) * L3_]     = rv[2 * j];
        out[ob + (size_t)(2 * j + 1) * L3_] = rv[2 * j + 1];
    }
#pragma unroll
    for (int j = 0; j < 8; ++j) qv[j] = rv[j] * rv[j];
#pragma unroll
    for (int off = 32; off > 0; off >>= 1) {
#pragma unroll
        for (int j = 0; j < 8; ++j) {
            rv[j] += __shfl_down(rv[j], off);
            qv[j] += __shfl_down(qv[j], off);
        }
    }
    __shared__ float red3[4][16];
    if ((tid & 63) == 0) {
        const int wv = tid >> 6;
#pragma unroll
        for (int j = 0; j < 8; ++j) { red3[wv][j] = rv[j]; red3[wv][8 + j] = qv[j]; }
    }
    __syncthreads();
    if (tid < 16) {
        const float a = red3[0][tid] + red3[1][tid] + red3[2][tid] + red3[3][tid];
        atomicAdd(&stats3[(tid >= 8 ? 32 : 0) + o0 + (tid & 7)], a);
    }
}

// ---------------------------------------------------------------------------
// Fused conv4 + BN3-affine DWT + conv5 + per-(b,ch) stats. y4/y5 are never
// materialized — only their per-(b,ch) sums/sumsqs survive (all the tail
// needs). grid(32), block 512.
__global__ __launch_bounds__(512) void tail_fused_kernel(
        const float* __restrict__ y3, const float* __restrict__ w4t,
        const float* __restrict__ b4t, const float* __restrict__ w5,
        const float* __restrict__ b5, const float* __restrict__ stats3,
        const float* __restrict__ g3, const float* __restrict__ be3,
        float* __restrict__ part) {
    const int b = blockIdx.x, l = threadIdx.x;  // l in [0,512)
    __shared__ float cm[L3_];
    __shared__ float bands[5][L3_];
    __shared__ float w5s[240];
    __shared__ float b5s[16], b4s[16];
    __shared__ float sc3s[32], sh3s[32];
    __shared__ float redf[8][64];
    if (l < 240) w5s[l] = w5[l];
    if (l < 16) { b5s[l] = b5[l]; b4s[l] = b4t[l]; }
    if (l >= 256 && l < 288) {
        const int ch = l - 256;
        const float n = (float)(B_ * L3_);
        const float m = stats3[ch] / n;
        const float v = stats3[32 + ch] / n - m * m;
        const float sc = rsqrtf(v + 1e-5f) * g3[ch];
        sc3s[ch] = sc;
        sh3s[ch] = be3[ch] - m * sc;
    }
    __syncthreads();
    // conv4 (BN3 folded weights) at position l -> a4 (post-relu later)
    v2f a4[8];
    const v2f* b4s2 = (const v2f*)b4s;
#pragma unroll
    for (int j = 0; j < 8; ++j) a4[j] = (v2f){0.f, 0.f};
    const float* yb = y3 + (size_t)b * 32 * L3_ + l;
    if (l < L4_) {
#pragma unroll
        for (int j = 0; j < 8; ++j) a4[j] = b4s2[j];
        for (int c = 0; c < 32; ++c) {
            const float x0 = yb[c * L3_], x1 = yb[c * L3_ + 1], x2 = yb[c * L3_ + 2];
            const v2f vx0 = {x0, x0}, vx1 = {x1, x1}, vx2 = {x2, x2};
            const v2f* wc = (const v2f*)(w4t + (size_t)c * 48);   // k-stride 8 v2f
#pragma unroll
            for (int j = 0; j < 8; ++j)
                a4[j] = __builtin_elementwise_fma(wc[j], vx0,
                        __builtin_elementwise_fma(wc[8 + j], vx1,
                        __builtin_elementwise_fma(wc[16 + j], vx2, a4[j])));
        }
    }
    // BN3-affine channel mean for DWT
    {
        float s = 0.f, shs = 0.f;
        for (int ch = 0; ch < 32; ++ch) {
            s = fmaf(yb[ch * L3_], sc3s[ch], s);
            shs += sh3s[ch];
        }
        cm[l] = (s + shs) * (1.f / 32.f);
    }
    __syncthreads();
    const float s1 = 0.70710678118654752440f;
    const float s2c = 0.5f;
    const float s3 = 0.35355339059327378f;
    const float s4 = 0.25f;
    const int b16 = l & ~15, b8 = l & ~7, b4v = l & ~3, b2v = l & ~1;
    float sa = 0.f, sb = 0.f;
#pragma unroll
    for (int i = 0; i < 8; ++i) { sa += cm[b16 + i]; sb += cm[b16 + 8 + i]; }
    bands[0][l] = (sa + sb) * s4;
    bands[1][l] = (sa - sb) * s4;
    float ta = 0.f, tb = 0.f;
#pragma unroll
    for (int i = 0; i < 4; ++i) { ta += cm[b8 + i]; tb += cm[b8 + 4 + i]; }
    bands[2][l] = (ta - tb) * s3;
    bands[3][l] = (cm[b4v] + cm[b4v + 1] - cm[b4v + 2] - cm[b4v + 3]) * s2c;
    bands[4][l] = (cm[b2v] - cm[b2v + 1]) * s1;
    __syncthreads();
    // conv5 at position l -> vals in registers
    float s4v[16], q4v[16], s5v[16], q5v[16];
#pragma unroll
    for (int o = 0; o < 16; ++o) { s5v[o] = 0.f; }
    if (l < L4_) {
        float in3[5][3];
#pragma unroll
        for (int c = 0; c < 5; ++c) {
            in3[c][0] = bands[c][l]; in3[c][1] = bands[c][l + 1]; in3[c][2] = bands[c][l + 2];
        }
#pragma unroll
        for (int o = 0; o < 16; ++o) {
            float acc = b5s[o];
#pragma unroll
            for (int c = 0; c < 5; ++c) {
                const float* wp = &w5s[(o * 5 + c) * 3];
                acc += in3[c][0] * wp[0] + in3[c][1] * wp[1] + in3[c][2] * wp[2];
            }
            s5v[o] = fmaxf(acc, 0.f);
        }
    }
    // per-(b,ch) sums: s4,q4 from conv4; s5,q5 from conv5
#pragma unroll
    for (int j = 0; j < 8; ++j) {
        const float v0 = (l < L4_) ? fmaxf(a4[j].x, 0.f) : 0.f;
        const float v1 = (l < L4_) ? fmaxf(a4[j].y, 0.f) : 0.f;
        s4v[2 * j] = v0; s4v[2 * j + 1] = v1;
        q4v[2 * j] = v0 * v0; q4v[2 * j + 1] = v1 * v1;
    }
#pragma unroll
    for (int o = 0; o < 16; ++o) q5v[o] = s5v[o] * s5v[o];
#pragma unroll
    for (int off = 32; off > 0; off >>= 1) {
#pragma unroll
        for (int o = 0; o < 16; ++o) {
            s4v[o] += __shfl_down(s4v[o], off);
            q4v[o] += __shfl_down(q4v[o], off);
            s5v[o] += __shfl_down(s5v[o], off);
            q5v[o] += __shfl_down(q5v[o], off);
        }
    }
    if ((l & 63) == 0) {
        const int wv = l >> 6;
#pragma unroll
        for (int o = 0; o < 16; ++o) {
            redf[wv][o]      = s4v[o];
            redf[wv][16 + o] = q4v[o];
            redf[wv][32 + o] = s5v[o];
            redf[wv][48 + o] = q5v[o];
        }
    }
    __syncthreads();
    if (l < 64) {
        float a = 0.f;
#pragma unroll
        for (int wv = 0; wv < 8; ++wv) a += redf[wv][l];
        // component 0=s4,1=q4,2=s5,3=q5 for channel l&15
        part[(size_t)(b * 16 + (l & 15)) * 4 + (l >> 4)] = a;
    }
}

// Tail stage B: BN4/BN5 stats + pooling(+affine) + FC. grid(1), block 512.
__global__ __launch_bounds__(512) void tail_final_kernel(
        const float* __restrict__ part,
        const float* __restrict__ g4, const float* __restrict__ be4,
        const float* __restrict__ g5, const float* __restrict__ be5,
        const float* __restrict__ fcw, const float* __restrict__ fcb,
        float* __restrict__ out) {
    const int p = threadIdx.x;           // 0..511
    const int b = p >> 4, ch = p & 15;
    const float4 v = ((const float4*)part)[b * 16 + ch];  // s4,q4,s5,q5
    __shared__ float S4[512], Q4[512], S5[512], Q5[512];
    __shared__ float M4[16], R4[16], M5[16], R5[16];
    __shared__ float pool[B_][16];
    S4[p] = v.x; Q4[p] = v.y; S5[p] = v.z; Q5[p] = v.w;
    __syncthreads();
    if (p < 16) {
        float ts = 0.f, tq = 0.f, us = 0.f, uq = 0.f;
        for (int bb = 0; bb < B_; ++bb) {
            ts += S4[bb * 16 + p]; tq += Q4[bb * 16 + p];
            us += S5[bb * 16 + p]; uq += Q5[bb * 16 + p];
        }
        const float n = (float)(B_ * L4_);
        float m = ts / n; M4[p] = m; R4[p] = rsqrtf(tq / n - m * m + 1e-5f);
        m = us / n;       M5[p] = m; R5[p] = rsqrtf(uq / n - m * m + 1e-5f);
    }
    __syncthreads();
    {
        const float mm4 = v.x / (float)L4_, mm5 = v.z / (float)L4_;
        const float v4 = (mm4 - M4[ch]) * R4[ch] * g4[ch] + be4[ch];
        const float v5 = (mm5 - M5[ch]) * R5[ch] * g5[ch] + be5[ch];
        pool[b][ch] = 0.5f * (v4 + v5);
    }
    __syncthreads();
    if (p < B_ * 10) {
        const int bb = p / 10, row = p - bb * 10;
        float a = fcb[row];
#pragma unroll
        for (int c = 0; c < 16; ++c) a += pool[bb][c] * fcw[row * 16 + c];
        out[bb * 10 + row] = a;
    }
}

// ---------------------------------------------------------------------------
extern "C" void kernel_launch(void* const* d_in, const int* in_sizes, int n_in,
                              void* d_out, int out_size, void* d_ws, size_t ws_size,
                              hipStream_t stream) {
    (void)in_sizes; (void)n_in; (void)out_size; (void)ws_size;
    const float* x   = (const float*)d_in[0];
    const float* wif = (const float*)d_in[1];
    const float* whf = (const float*)d_in[2];
    const float* bf  = (const float*)d_in[3];
    const float* wir = (const float*)d_in[4];
    const float* whr = (const float*)d_in[5];
    const float* br  = (const float*)d_in[6];
    const float* bw  = (const float*)d_in[7];
    const float* bb  = (const float*)d_in[8];
    const float* g1  = (const float*)d_in[9];  const float* be1 = (const float*)d_in[10];
    const float* g2  = (const float*)d_in[11]; const float* be2 = (const float*)d_in[12];
    const float* g3  = (const float*)d_in[13]; const float* be3 = (const float*)d_in[14];
    const float* g4  = (const float*)d_in[15]; const float* be4 = (const float*)d_in[16];
    const float* g5  = (const float*)d_in[17]; const float* be5 = (const float*)d_in[18];
    const float* w2  = (const float*)d_in[19]; const float* b2  = (const float*)d_in[20];
    const float* w3  = (const float*)d_in[21]; const float* b3  = (const float*)d_in[22];
    const float* w4  = (const float*)d_in[23]; const float* b4  = (const float*)d_in[24];
    const float* w5  = (const float*)d_in[25]; const float* b5  = (const float*)d_in[26];
    const float* fcw = (const float*)d_in[27]; const float* fcb = (const float*)d_in[28];
    float* out = (float*)d_out;
    float* ws  = (float*)d_ws;

    // Workspace layout (floats). xg region is reused by `wave` after the LSTM.
    float* xg_f  = ws;                       //  4,243,456
    float* xg_r  = ws + 4243456;             //  4,243,456
    float* wave  = ws;                       // 12,730,368 (reuses xg region)
    float* X     = ws + 12730368;            //  2,121,728 (dead after wave_kernel)
    float* y2    = ws + 14852096;            //  2,113,536
    float* y3    = ws + 16965632;            //    524,288
    float* stats = ws + 18012160;            //      1,536 (BN1 s/s2)
    float* m1 = ws + 18013696; float* r1 = m1 + 768;
    float* tpart  = r1 + 768;                //      2,048 (tail partials)
    float* stats2 = tpart + 2048;            //        256 (BN2 raw s/s2)
    float* stats3 = stats2 + 256;            //         64 (BN3 raw s/s2)
    // Folded weights live in the dead X region (X only read by wave_kernel):
    float* w2t  = X;                  // 294,912
    float* b2t  = X + 294912;         //     128
    float* w3t  = X + 295040;         //  20,480
    float* b3t  = X + 315520;         //      32
    float* w4t  = X + 315552;         //   1,536
    float* b4t  = X + 317088;         //      16

    // 1) input projections + zero BN1/BN2/BN3 stats
    xg_kernel<<<dim3(65, 32), 256, 0, stream>>>(x, wif, bf, wir, br, xg_f, xg_r,
                                                stats, stats2);
    // 2) bidirectional LSTM recurrence -> X (frozen R0 structure)
    lstm_kernel<<<dim3(64), 128, 0, stream>>>(xg_f, xg_r, whf, whr, X);
    // 3) wave module -> wave (raw), fused BN1 partial stats
    wave_kernel<<<dim3(3, CCH, B_), 256, 0, stream>>>(X, bw, bb, wave, stats);
    bn1_finalize_kernel<<<dim3(1), 768, 0, stream>>>(stats, m1, r1);
    // 4) fold BN1 into conv2 weights; conv2 on raw wave (+BN2 stats)
    bnfold2_kernel<<<dim3(128), 256, 0, stream>>>(w2, b2, m1, r1, g1, be1, w2t, b2t);
    conv2_kernel<<<dim3(32, 3, 8), 256, 0, stream>>>(wave, w2t, b2t, y2, stats2);
    // 5) fold BN2 (inline finalize) into conv3; conv3 (+BN3 stats)
    bnfold3_kernel<<<dim3(32), 256, 0, stream>>>(w3, b3, stats2, g2, be2, w3t, b3t);
    conv3_kernel<<<dim3(32, 2, 4), 256, 0, stream>>>(y2, w3t, b3t, y3, stats3);
    // 6) fold BN3 (inline finalize) into conv4 weights
    bnfold4_kernel<<<dim3(16), 128, 0, stream>>>(w4, b4, stats3, g3, be3, w4t, b4t);
    // 7) fused conv4 + DWT + conv5 + per-(b,ch) stats (no y4/y5 materialization)
    tail_fused_kernel<<<dim3(B_), 512, 0, stream>>>(y3, w4t, b4t, w5, b5,
                                                    stats3, g3, be3, tpart);
    // 8) BN4/BN5 stats + pooling + FC
    tail_final_kernel<<<dim3(1), 512, 0, stream>>>(tpart, g4, be4, g5, be5, fcw, fcb, out);
}

// Round 10
// 881.512 us; speedup vs baseline: 1.3077x; 1.0003x over previous
//
#include <hip/hip_runtime.h>
#include <math.h>

// Problem constants
#define B_     32
#define F_     64
#define T_     518
#define HID    64
#define GATES  256   // 4*HID
#define CCH    128   // 2*HID lstm output channels
#define NWAVE  6
#define WCH    768   // NWAVE*CCH
#define L2_    516   // T-2   (conv2 out)
#define L3_    512   // L2-4  (conv3 out)
#define L4_    510   // L3-2  (conv4/conv5 out)

typedef float v2f __attribute__((ext_vector_type(2)));
typedef _Float16 h2 __attribute__((ext_vector_type(2)));

__device__ __forceinline__ float frcp(float x) { return __builtin_amdgcn_rcpf(x); }
__device__ __forceinline__ float fsigmoid(float x) { return frcp(1.f + __expf(-x)); }
__device__ __forceinline__ float ftanh(float x) { return 1.f - 2.f * frcp(1.f + __expf(2.f * x)); }

__device__ __forceinline__ float fdot2(h2 a, h2 b, float c) {
#if __has_builtin(__builtin_amdgcn_fdot2)
    return __builtin_amdgcn_fdot2(a, b, c, false);
#else
    return fmaf((float)a[0], (float)b[0], fmaf((float)a[1], (float)b[1], c));
#endif
}

// ---------------------------------------------------------------------------
// K0: pack Whh (both dirs) to fp16 pairs: w16[row][i] = (w[row][2i], w[row][2i+1]).
// 1 block, 256 threads (one gate row each).
__global__ void packw_kernel(const float* __restrict__ whf, const float* __restrict__ whr,
                             h2* __restrict__ w16f, h2* __restrict__ w16r) {
    const int row = threadIdx.x;
    const float* sf = whf + (size_t)row * HID;
    const float* sr = whr + (size_t)row * HID;
#pragma unroll
    for (int i = 0; i < 32; ++i) {
        w16f[row * 32 + i] = (h2){(_Float16)sf[2 * i], (_Float16)sf[2 * i + 1]};
        w16r[row * 32 + i] = (h2){(_Float16)sr[2 * i], (_Float16)sr[2 * i + 1]};
    }
}

// ---------------------------------------------------------------------------
// K1: input projections, both dirs. Output layout xg[t][w][r][g2] (coalesced).
// Also zeroes BN1 stats (1536) and BN2/BN3 raw stats (320).
__global__ void xg_kernel(const float* __restrict__ x,
                          const float* __restrict__ wif, const float* __restrict__ bf,
                          const float* __restrict__ wir, const float* __restrict__ br,
                          float* __restrict__ xg_f, float* __restrict__ xg_r,
                          float* __restrict__ stats, float* __restrict__ stats23) {
    if (blockIdx.x == 0 && blockIdx.y == 0) {
        for (int i = threadIdx.x; i < 2 * WCH; i += 256) stats[i] = 0.f;
        if (threadIdx.x < 320) stats23[threadIdx.x] = 0.f;   // 256 BN2 + 64 BN3
    }
    const int tid = threadIdx.x;
    const int wv  = tid >> 7;
    const int g2  = tid & 1;
    const int r   = (tid >> 1) & 63;
    const int g   = (2 * wv + g2) * 64 + r;       // gate row; store offset == tid
    const int b   = blockIdx.y;
    const int t0  = blockIdx.x * 8;
    float4 wa[16], wb[16];
    const float4* w0 = (const float4*)(wif + g * F_);
    const float4* w1 = (const float4*)(wir + g * F_);
#pragma unroll
    for (int i = 0; i < 16; ++i) { wa[i] = w0[i]; wb[i] = w1[i]; }
    const float bfv = bf[g], brv = br[g];
    for (int tt = 0; tt < 8; ++tt) {
        const int t = t0 + tt;
        if (t >= T_) break;
        const float* xp = x + (size_t)b * F_ * T_ + t;
        float a0 = bfv, a1 = brv;
#pragma unroll
        for (int i = 0; i < 16; ++i) {
            float x0 = xp[(i * 4 + 0) * T_];
            float x1 = xp[(i * 4 + 1) * T_];
            float x2 = xp[(i * 4 + 2) * T_];
            float x3 = xp[(i * 4 + 3) * T_];
            a0 += wa[i].x * x0 + wa[i].y * x1 + wa[i].z * x2 + wa[i].w * x3;
            a1 += wb[i].x * x0 + wb[i].y * x1 + wb[i].z * x2 + wb[i].w * x3;
        }
        const size_t o = ((size_t)b * T_ + t) * GATES + tid;   // coalesced
        xg_f[o] = a0;
        xg_r[o] = a1;
    }
}

// ---------------------------------------------------------------------------
// K2: LSTM recurrence — R0 2-wave structure, fp16 weights + fp16 h exchange,
// fp32 state/accum via v_dot2_f32_f16. Halves weight bytes/step (the proven
// bound) and halves matvec issue. Weight regs = 64 VGPRs (< allocator's ~150
// remat threshold — may finally go resident). grid(64), block 128.
__global__ __launch_bounds__(128, 1) void lstm_kernel(
        const float* __restrict__ xgi_f, const float* __restrict__ xgi_r,
        const h2* __restrict__ w16f, const h2* __restrict__ w16r,
        float* __restrict__ X) {
    const int dir = blockIdx.x & 1;
    const int b   = blockIdx.x >> 1;
    const float* xg  = (dir ? xgi_r : xgi_f) + (size_t)b * T_ * GATES;
    const h2* w16 = dir ? w16r : w16f;
    const int tid = threadIdx.x;
    const int r   = tid & 63;
    const int w   = tid >> 6;            // wave 0: gates i,f ; wave 1: gates g,o

    union U4 { uint4 u; h2 h[4]; };
    U4 wA[8], wB[8];                     // 32 pairs per gate row = 8 uint4 each
    {
        const uint4* pA = (const uint4*)(w16 + (size_t)((2 * w) * HID + r) * 32);
        const uint4* pB = (const uint4*)(w16 + (size_t)((2 * w + 1) * HID + r) * 32);
#pragma unroll
        for (int i = 0; i < 8; ++i) { wA[i].u = pA[i]; wB[i].u = pB[i]; }
    }

    __shared__ __align__(16) _Float16 hs16[2][HID];   // per-wave fp16 h copy
    __shared__ __align__(16) float gbuf[2][HID][4];   // double-buffered gates
    hs16[w][r] = (_Float16)0.f;
    float c = 0.f;
    float* Xrow = X + ((size_t)(b * CCH + dir * HID + r)) * T_;

    int t = dir ? (T_ - 1) : 0;
    const int step = dir ? -1 : 1;
    const float2* xg2 = (const float2*)xg;   // index (t*2 + w)*64 + r
    float2 q0 = xg2[((size_t)t * 2 + w) * 64 + r];
    float2 q1 = xg2[((size_t)(t + step) * 2 + w) * 64 + r];

    for (int s = 0; s < T_; ++s) {
        float a0 = q0.x, a0b = 0.f;
        float a1 = q0.y, a1b = 0.f;
        const uint4* hp4 = (const uint4*)hs16[w];
#pragma unroll
        for (int i = 0; i < 8; ++i) {
            U4 hv; hv.u = hp4[i];
            a0  = fdot2(wA[i].h[0], hv.h[0], a0);
            a0b = fdot2(wA[i].h[1], hv.h[1], a0b);
            a0  = fdot2(wA[i].h[2], hv.h[2], a0);
            a0b = fdot2(wA[i].h[3], hv.h[3], a0b);
            a1  = fdot2(wB[i].h[0], hv.h[0], a1);
            a1b = fdot2(wB[i].h[1], hv.h[1], a1b);
            a1  = fdot2(wB[i].h[2], hv.h[2], a1);
            a1b = fdot2(wB[i].h[3], hv.h[3], a1b);
        }
        const float gA = a0 + a0b;
        const float gB = a1 + a1b;
        const int buf = s & 1;
        *(float2*)&gbuf[buf][r][2 * w] = make_float2(gA, gB);

        int tp = t + 2 * step;
        tp = tp < 0 ? 0 : (tp >= T_ ? T_ - 1 : tp);
        const float2 qn = xg2[((size_t)tp * 2 + w) * 64 + r];

        asm volatile("s_waitcnt lgkmcnt(0)" ::: "memory");
        __builtin_amdgcn_s_barrier();

        const float4 g4 = *(const float4*)gbuf[buf][r];   // i,f,g,o
        const float si = fsigmoid(g4.x);
        const float sf = fsigmoid(g4.y);
        const float so = fsigmoid(g4.w);
        c = sf * c + si * ftanh(g4.z);
        const float h = so * ftanh(c);

        hs16[w][r] = (_Float16)h;
        if (w == 0) Xrow[t] = h;
        q0 = q1; q1 = qn;
        t += step;
    }
}

// ---------------------------------------------------------------------------
// K3: wave module + fused BN1 partial stats. grid(3, 128, 32), block 256
__global__ void wave_kernel(const float* __restrict__ X,
                            const float* __restrict__ bw, const float* __restrict__ bb,
                            float* __restrict__ wave, float* __restrict__ stats) {
    const int b = blockIdx.z, c = blockIdx.y;
    const int t0 = blockIdx.x * 256;
    const int tid = threadIdx.x;
    __shared__ float xs[256 + 14];
    __shared__ float bws[NWAVE][16];
    __shared__ float bbs[NWAVE];
    __shared__ float red[4][12];
    const float* xrow = X + ((size_t)(b * CCH + c)) * T_;
    for (int i = tid; i < 270; i += 256) {
        int tt = t0 - 7 + i;
        xs[i] = (tt >= 0 && tt < T_) ? xrow[tt] : 0.f;
    }
    if (tid < NWAVE * 15) bws[tid / 15][tid % 15] = bw[tid];
    if (tid < NWAVE) bbs[tid] = bb[tid];
    __syncthreads();
    const int t = t0 + tid;
    float ls[NWAVE], lq[NWAVE];
#pragma unroll
    for (int ii = 0; ii < NWAVE; ++ii) { ls[ii] = 0.f; lq[ii] = 0.f; }
    if (t < T_) {
        float win[15];
#pragma unroll
        for (int k = 0; k < 15; ++k) win[k] = xs[tid + k];
        float e[8];
        e[0] = win[7];
#pragma unroll
        for (int m = 1; m < 8; ++m) e[m] = win[7 - m] + win[7 + m];
        const float c0 = 6.28318530717958647692f / 15.f;  // 2*pi/WIDE
#pragma unroll
        for (int ii = 0; ii < NWAVE; ++ii) {
            float sc = bbs[ii];
#pragma unroll
            for (int k = 0; k < 15; ++k) sc += win[k] * bws[ii][k];
            sc = fmaxf(sc, 0.f);
            const float phi = c0 * (float)(ii + 1) * sc;
            float o = e[0];
#pragma unroll
            for (int m = 1; m < 8; ++m) o += e[m] * __cosf(phi * (float)m);
            const float q = (truncf(sc * 15.f) + 1.f) * (2.f / 17.f);
            const float val = o * rsqrtf(q);
            wave[((size_t)(b * WCH + ii * CCH + c)) * T_ + t] = val;
            ls[ii] = val;
            lq[ii] = val * val;
        }
    }
#pragma unroll
    for (int off = 32; off > 0; off >>= 1) {
#pragma unroll
        for (int ii = 0; ii < NWAVE; ++ii) {
            ls[ii] += __shfl_down(ls[ii], off);
            lq[ii] += __shfl_down(lq[ii], off);
        }
    }
    if ((tid & 63) == 0) {
        const int w = tid >> 6;
#pragma unroll
        for (int ii = 0; ii < NWAVE; ++ii) { red[w][ii] = ls[ii]; red[w][6 + ii] = lq[ii]; }
    }
    __syncthreads();
    if (tid < 12) {
        const float a = red[0][tid] + red[1][tid] + red[2][tid] + red[3][tid];
        const int ii = tid % 6;
        const int ch = ii * CCH + c;
        atomicAdd(&stats[(tid >= 6 ? WCH : 0) + ch], a);
    }
}

// Finalize BN1 stats: 1 block, 768 threads
__global__ void bn1_finalize_kernel(const float* __restrict__ stats,
                                    float* __restrict__ mean, float* __restrict__ rstd) {
    const int c = threadIdx.x;
    const float n = (float)(B_ * T_);
    const float m = stats[c] / n;
    const float v = stats[WCH + c] / n - m * m;
    mean[c] = m;
    rstd[c] = rsqrtf(v + 1e-5f);
}

// ---------------------------------------------------------------------------
// bnfold2: grid(128), block 256 (one block per output channel)
__global__ void bnfold2_kernel(const float* __restrict__ w2, const float* __restrict__ b2,
                               const float* __restrict__ m1, const float* __restrict__ r1,
                               const float* __restrict__ g1, const float* __restrict__ be1,
                               float* __restrict__ w2t, float* __restrict__ b2t) {
    const int o = blockIdx.x, tid = threadIdx.x;
    float part = 0.f;
    for (int idx = tid; idx < WCH * 3; idx += 256) {
        const int c = idx / 3;
        const float sc = r1[c] * g1[c];
        const float sh = be1[c] - m1[c] * sc;
        const float wv = w2[(size_t)o * (WCH * 3) + idx];
        w2t[(size_t)idx * 128 + o] = wv * sc;
        part += wv * sh;
    }
#pragma unroll
    for (int off = 32; off > 0; off >>= 1) part += __shfl_down(part, off);
    __shared__ float red[4];
    if ((tid & 63) == 0) red[tid >> 6] = part;
    __syncthreads();
    if (tid == 0) b2t[o] = b2[o] + red[0] + red[1] + red[2] + red[3];
}

// bnfold3 (BN2 finalize inline from raw stats2): grid(32), block 256
__global__ void bnfold3_kernel(const float* __restrict__ w3, const float* __restrict__ b3,
                               const float* __restrict__ stats2,
                               const float* __restrict__ g2, const float* __restrict__ be2,
                               float* __restrict__ w3t, float* __restrict__ b3t) {
    const int o = blockIdx.x, tid = threadIdx.x;
    __shared__ float sc2s[128], sh2s[128];
    if (tid < 128) {
        const float n = (float)(B_ * L2_);
        const float m = stats2[tid] / n;
        const float v = stats2[128 + tid] / n - m * m;
        const float sc = rsqrtf(v + 1e-5f) * g2[tid];
        sc2s[tid] = sc;
        sh2s[tid] = be2[tid] - m * sc;
    }
    __syncthreads();
    float part = 0.f;
    for (int idx = tid; idx < 128 * 5; idx += 256) {
        const int c = idx / 5;
        const float wv = w3[(size_t)o * 640 + idx];
        w3t[(size_t)idx * 32 + o] = wv * sc2s[c];
        part += wv * sh2s[c];
    }
#pragma unroll
    for (int off = 32; off > 0; off >>= 1) part += __shfl_down(part, off);
    __shared__ float red[4];
    if ((tid & 63) == 0) red[tid >> 6] = part;
    __syncthreads();
    if (tid == 0) b3t[o] = b3[o] + red[0] + red[1] + red[2] + red[3];
}

// bnfold4 (BN3 finalize inline from raw stats3): grid(16), block 128
__global__ void bnfold4_kernel(const float* __restrict__ w4, const float* __restrict__ b4,
                               const float* __restrict__ stats3,
                               const float* __restrict__ g3, const float* __restrict__ be3,
                               float* __restrict__ w4t, float* __restrict__ b4t) {
    const int o = blockIdx.x, tid = threadIdx.x;
    __shared__ float sc3s[32], sh3s[32];
    if (tid < 32) {
        const float n = (float)(B_ * L3_);
        const float m = stats3[tid] / n;
        const float v = stats3[32 + tid] / n - m * m;
        const float sc = rsqrtf(v + 1e-5f) * g3[tid];
        sc3s[tid] = sc;
        sh3s[tid] = be3[tid] - m * sc;
    }
    __syncthreads();
    float part = 0.f;
    if (tid < 96) {
        const int c = tid / 3;
        const float wv = w4[(size_t)o * 96 + tid];
        w4t[(size_t)tid * 16 + o] = wv * sc3s[c];
        part = wv * sh3s[c];
    }
#pragma unroll
    for (int off = 32; off > 0; off >>= 1) part += __shfl_down(part, off);
    __shared__ float red[2];
    if ((tid & 63) == 0) red[tid >> 6] = part;
    __syncthreads();
    if (tid == 0) b4t[o] = b4[o] + red[0] + red[1];
}

// ---------------------------------------------------------------------------
// conv2 (BN1 folded) + fused BN2 partial stats: grid(32 b, 3 t, 8 o), block 256
__global__ __launch_bounds__(256) void conv2_kernel(
        const float* __restrict__ in, const float* __restrict__ wt,
        const float* __restrict__ bt, float* __restrict__ out,
        float* __restrict__ stats2) {
    const int b  = blockIdx.x;
    const int tid = threadIdx.x;
    const int t  = blockIdx.y * 256 + tid;
    const int o0 = blockIdx.z * 16;
    float rv[16], qv[16];
#pragma unroll
    for (int j = 0; j < 16; ++j) rv[j] = 0.f;
    if (t < L2_) {
        v2f acc[8];
        const v2f* bt2 = (const v2f*)(bt + o0);
#pragma unroll
        for (int j = 0; j < 8; ++j) acc[j] = bt2[j];
        const float* inb = in + (size_t)b * WCH * T_ + t;
        for (int c = 0; c < WCH; ++c) {
            const float x0 = inb[c * T_], x1 = inb[c * T_ + 1], x2 = inb[c * T_ + 2];
            const v2f vx0 = {x0, x0}, vx1 = {x1, x1}, vx2 = {x2, x2};
            const v2f* wc = (const v2f*)(wt + (size_t)c * 384 + o0);  // k-stride 64 v2f
#pragma unroll
            for (int j = 0; j < 8; ++j)
                acc[j] = __builtin_elementwise_fma(wc[j], vx0,
                         __builtin_elementwise_fma(wc[64 + j], vx1,
                         __builtin_elementwise_fma(wc[128 + j], vx2, acc[j])));
        }
        const size_t ob = ((size_t)b * 128 + o0) * L2_ + t;
#pragma unroll
        for (int j = 0; j < 8; ++j) {
            rv[2 * j]     = fmaxf(acc[j].x, 0.f);
            rv[2 * j + 1] = fmaxf(acc[j].y, 0.f);
            out[ob + (size_t)(2 * j) * L2_]     = rv[2 * j];
            out[ob + (size_t)(2 * j + 1) * L2_] = rv[2 * j + 1];
        }
    }
#pragma unroll
    for (int j = 0; j < 16; ++j) qv[j] = rv[j] * rv[j];
#pragma unroll
    for (int off = 32; off > 0; off >>= 1) {
#pragma unroll
        for (int j = 0; j < 16; ++j) {
            rv[j] += __shfl_down(rv[j], off);
            qv[j] += __shfl_down(qv[j], off);
        }
    }
    __shared__ float red2[4][32];
    if ((tid & 63) == 0) {
        const int wv = tid >> 6;
#pragma unroll
        for (int j = 0; j < 16; ++j) { red2[wv][j] = rv[j]; red2[wv][16 + j] = qv[j]; }
    }
    __syncthreads();
    if (tid < 32) {
        const float a = red2[0][tid] + red2[1][tid] + red2[2][tid] + red2[3][tid];
        atomicAdd(&stats2[(tid >= 16 ? 128 : 0) + o0 + (tid & 15)], a);
    }
}

// conv3 (BN2 folded) + fused BN3 partial stats: grid(32 b, 2 t, 4 o), block 256
__global__ __launch_bounds__(256) void conv3_kernel(
        const float* __restrict__ in, const float* __restrict__ wt,
        const float* __restrict__ bt, float* __restrict__ out,
        float* __restrict__ stats3) {
    const int b  = blockIdx.x;
    const int tid = threadIdx.x;
    const int t  = blockIdx.y * 256 + tid;   // < 512 always
    const int o0 = blockIdx.z * 8;
    v2f acc[4];
    const v2f* bt2 = (const v2f*)(bt + o0);
#pragma unroll
    for (int j = 0; j < 4; ++j) acc[j] = bt2[j];
    const float* inb = in + (size_t)b * 128 * L2_ + t;
    for (int c = 0; c < 128; ++c) {
        const float x0 = inb[c * L2_], x1 = inb[c * L2_ + 1], x2 = inb[c * L2_ + 2];
        const float x3 = inb[c * L2_ + 3], x4 = inb[c * L2_ + 4];
        const v2f vx0 = {x0, x0}, vx1 = {x1, x1}, vx2 = {x2, x2}, vx3 = {x3, x3}, vx4 = {x4, x4};
        const v2f* wc = (const v2f*)(wt + (size_t)c * 160 + o0);  // k-stride 16 v2f
#pragma unroll
        for (int j = 0; j < 4; ++j)
            acc[j] = __builtin_elementwise_fma(wc[j], vx0,
                     __builtin_elementwise_fma(wc[16 + j], vx1,
                     __builtin_elementwise_fma(wc[32 + j], vx2,
                     __builtin_elementwise_fma(wc[48 + j], vx3,
                     __builtin_elementwise_fma(wc[64 + j], vx4, acc[j])))));
    }
    const size_t ob = ((size_t)b * 32 + o0) * L3_ + t;
    float rv[8], qv[8];
#pragma unroll
    for (int j = 0; j < 4; ++j) {
        rv[2 * j]     = fmaxf(acc[j].x, 0.f);
        rv[2 * j + 1] = fmaxf(acc[j].y, 0.f);
        out[ob + (size_t)(2 * j) * L3_]     = rv[2 * j];
        out[ob + (size_t)(2 * j + 1) * L3_] = rv[2 * j + 1];
    }
#pragma unroll
    for (int j = 0; j < 8; ++j) qv[j] = rv[j] * rv[j];
#pragma unroll
    for (int off = 32; off > 0; off >>= 1) {
#pragma unroll
        for (int j = 0; j < 8; ++j) {
            rv[j] += __shfl_down(rv[j], off);
            qv[j] += __shfl_down(qv[j], off);
        }
    }
    __shared__ float red3[4][16];
    if ((tid & 63) == 0) {
        const int wv = tid >> 6;
#pragma unroll
        for (int j = 0; j < 8; ++j) { red3[wv][j] = rv[j]; red3[wv][8 + j] = qv[j]; }
    }
    __syncthreads();
    if (tid < 16) {
        const float a = red3[0][tid] + red3[1][tid] + red3[2][tid] + red3[3][tid];
        atomicAdd(&stats3[(tid >= 8 ? 32 : 0) + o0 + (tid & 7)], a);
    }
}

// ---------------------------------------------------------------------------
// Fused conv4 + BN3-affine DWT + conv5 + per-(b,ch) stats. y4/y5 never
// materialized. grid(32), block 512.
__global__ __launch_bounds__(512) void tail_fused_kernel(
        const float* __restrict__ y3, const float* __restrict__ w4t,
        const float* __restrict__ b4t, const float* __restrict__ w5,
        const float* __restrict__ b5, const float* __restrict__ stats3,
        const float* __restrict__ g3, const float* __restrict__ be3,
        float* __restrict__ part) {
    const int b = blockIdx.x, l = threadIdx.x;  // l in [0,512)
    __shared__ float cm[L3_];
    __shared__ float bands[5][L3_];
    __shared__ float w5s[240];
    __shared__ float b5s[16], b4s[16];
    __shared__ float sc3s[32], sh3s[32];
    __shared__ float redf[8][64];
    if (l < 240) w5s[l] = w5[l];
    if (l < 16) { b5s[l] = b5[l]; b4s[l] = b4t[l]; }
    if (l >= 256 && l < 288) {
        const int ch = l - 256;
        const float n = (float)(B_ * L3_);
        const float m = stats3[ch] / n;
        const float v = stats3[32 + ch] / n - m * m;
        const float sc = rsqrtf(v + 1e-5f) * g3[ch];
        sc3s[ch] = sc;
        sh3s[ch] = be3[ch] - m * sc;
    }
    __syncthreads();
    v2f a4[8];
    const v2f* b4s2 = (const v2f*)b4s;
#pragma unroll
    for (int j = 0; j < 8; ++j) a4[j] = (v2f){0.f, 0.f};
    const float* yb = y3 + (size_t)b * 32 * L3_ + l;
    if (l < L4_) {
#pragma unroll
        for (int j = 0; j < 8; ++j) a4[j] = b4s2[j];
        for (int c = 0; c < 32; ++c) {
            const float x0 = yb[c * L3_], x1 = yb[c * L3_ + 1], x2 = yb[c * L3_ + 2];
            const v2f vx0 = {x0, x0}, vx1 = {x1, x1}, vx2 = {x2, x2};
            const v2f* wc = (const v2f*)(w4t + (size_t)c * 48);   // k-stride 8 v2f
#pragma unroll
            for (int j = 0; j < 8; ++j)
                a4[j] = __builtin_elementwise_fma(wc[j], vx0,
                        __builtin_elementwise_fma(wc[8 + j], vx1,
                        __builtin_elementwise_fma(wc[16 + j], vx2, a4[j])));
        }
    }
    {
        float s = 0.f, shs = 0.f;
        for (int ch = 0; ch < 32; ++ch) {
            s = fmaf(yb[ch * L3_], sc3s[ch], s);
            shs += sh3s[ch];
        }
        cm[l] = (s + shs) * (1.f / 32.f);
    }
    __syncthreads();
    const float s1 = 0.70710678118654752440f;
    const float s2c = 0.5f;
    const float s3 = 0.35355339059327378f;
    const float s4 = 0.25f;
    const int b16 = l & ~15, b8 = l & ~7, b4v = l & ~3, b2v = l & ~1;
    float sa = 0.f, sb = 0.f;
#pragma unroll
    for (int i = 0; i < 8; ++i) { sa += cm[b16 + i]; sb += cm[b16 + 8 + i]; }
    bands[0][l] = (sa + sb) * s4;
    bands[1][l] = (sa - sb) * s4;
    float ta = 0.f, tb = 0.f;
#pragma unroll
    for (int i = 0; i < 4; ++i) { ta += cm[b8 + i]; tb += cm[b8 + 4 + i]; }
    bands[2][l] = (ta - tb) * s3;
    bands[3][l] = (cm[b4v] + cm[b4v + 1] - cm[b4v + 2] - cm[b4v + 3]) * s2c;
    bands[4][l] = (cm[b2v] - cm[b2v + 1]) * s1;
    __syncthreads();
    float s4v[16], q4v[16], s5v[16], q5v[16];
#pragma unroll
    for (int o = 0; o < 16; ++o) { s5v[o] = 0.f; }
    if (l < L4_) {
        float in3[5][3];
#pragma unroll
        for (int c = 0; c < 5; ++c) {
            in3[c][0] = bands[c][l]; in3[c][1] = bands[c][l + 1]; in3[c][2] = bands[c][l + 2];
        }
#pragma unroll
        for (int o = 0; o < 16; ++o) {
            float acc = b5s[o];
#pragma unroll
            for (int c = 0; c < 5; ++c) {
                const float* wp = &w5s[(o * 5 + c) * 3];
                acc += in3[c][0] * wp[0] + in3[c][1] * wp[1] + in3[c][2] * wp[2];
            }
            s5v[o] = fmaxf(acc, 0.f);
        }
    }
#pragma unroll
    for (int j = 0; j < 8; ++j) {
        const float v0 = (l < L4_) ? fmaxf(a4[j].x, 0.f) : 0.f;
        const float v1 = (l < L4_) ? fmaxf(a4[j].y, 0.f) : 0.f;
        s4v[2 * j] = v0; s4v[2 * j + 1] = v1;
        q4v[2 * j] = v0 * v0; q4v[2 * j + 1] = v1 * v1;
    }
#pragma unroll
    for (int o = 0; o < 16; ++o) q5v[o] = s5v[o] * s5v[o];
#pragma unroll
    for (int off = 32; off > 0; off >>= 1) {
#pragma unroll
        for (int o = 0; o < 16; ++o) {
            s4v[o] += __shfl_down(s4v[o], off);
            q4v[o] += __shfl_down(q4v[o], off);
            s5v[o] += __shfl_down(s5v[o], off);
            q5v[o] += __shfl_down(q5v[o], off);
        }
    }
    if ((l & 63) == 0) {
        const int wv = l >> 6;
#pragma unroll
        for (int o = 0; o < 16; ++o) {
            redf[wv][o]      = s4v[o];
            redf[wv][16 + o] = q4v[o];
            redf[wv][32 + o] = s5v[o];
            redf[wv][48 + o] = q5v[o];
        }
    }
    __syncthreads();
    if (l < 64) {
        float a = 0.f;
#pragma unroll
        for (int wv = 0; wv < 8; ++wv) a += redf[wv][l];
        part[(size_t)(b * 16 + (l & 15)) * 4 + (l >> 4)] = a;
    }
}

// Tail stage B: BN4/BN5 stats + pooling(+affine) + FC. grid(1), block 512.
__global__ __launch_bounds__(512) void tail_final_kernel(
        const float* __restrict__ part,
        const float* __restrict__ g4, const float* __restrict__ be4,
        const float* __restrict__ g5, const float* __restrict__ be5,
        const float* __restrict__ fcw, const float* __restrict__ fcb,
        float* __restrict__ out) {
    const int p = threadIdx.x;           // 0..511
    const int b = p >> 4, ch = p & 15;
    const float4 v = ((const float4*)part)[b * 16 + ch];  // s4,q4,s5,q5
    __shared__ float S4[512], Q4[512], S5[512], Q5[512];
    __shared__ float M4[16], R4[16], M5[16], R5[16];
    __shared__ float pool[B_][16];
    S4[p] = v.x; Q4[p] = v.y; S5[p] = v.z; Q5[p] = v.w;
    __syncthreads();
    if (p < 16) {
        float ts = 0.f, tq = 0.f, us = 0.f, uq = 0.f;
        for (int bb = 0; bb < B_; ++bb) {
            ts += S4[bb * 16 + p]; tq += Q4[bb * 16 + p];
            us += S5[bb * 16 + p]; uq += Q5[bb * 16 + p];
        }
        const float n = (float)(B_ * L4_);
        float m = ts / n; M4[p] = m; R4[p] = rsqrtf(tq / n - m * m + 1e-5f);
        m = us / n;       M5[p] = m; R5[p] = rsqrtf(uq / n - m * m + 1e-5f);
    }
    __syncthreads();
    {
        const float mm4 = v.x / (float)L4_, mm5 = v.z / (float)L4_;
        const float v4 = (mm4 - M4[ch]) * R4[ch] * g4[ch] + be4[ch];
        const float v5 = (mm5 - M5[ch]) * R5[ch] * g5[ch] + be5[ch];
        pool[b][ch] = 0.5f * (v4 + v5);
    }
    __syncthreads();
    if (p < B_ * 10) {
        const int bb = p / 10, row = p - bb * 10;
        float a = fcb[row];
#pragma unroll
        for (int c = 0; c < 16; ++c) a += pool[bb][c] * fcw[row * 16 + c];
        out[bb * 10 + row] = a;
    }
}

// ---------------------------------------------------------------------------
extern "C" void kernel_launch(void* const* d_in, const int* in_sizes, int n_in,
                              void* d_out, int out_size, void* d_ws, size_t ws_size,
                              hipStream_t stream) {
    (void)in_sizes; (void)n_in; (void)out_size; (void)ws_size;
    const float* x   = (const float*)d_in[0];
    const float* wif = (const float*)d_in[1];
    const float* whf = (const float*)d_in[2];
    const float* bf  = (const float*)d_in[3];
    const float* wir = (const float*)d_in[4];
    const float* whr = (const float*)d_in[5];
    const float* br  = (const float*)d_in[6];
    const float* bw  = (const float*)d_in[7];
    const float* bb  = (const float*)d_in[8];
    const float* g1  = (const float*)d_in[9];  const float* be1 = (const float*)d_in[10];
    const float* g2  = (const float*)d_in[11]; const float* be2 = (const float*)d_in[12];
    const float* g3  = (const float*)d_in[13]; const float* be3 = (const float*)d_in[14];
    const float* g4  = (const float*)d_in[15]; const float* be4 = (const float*)d_in[16];
    const float* g5  = (const float*)d_in[17]; const float* be5 = (const float*)d_in[18];
    const float* w2  = (const float*)d_in[19]; const float* b2  = (const float*)d_in[20];
    const float* w3  = (const float*)d_in[21]; const float* b3  = (const float*)d_in[22];
    const float* w4  = (const float*)d_in[23]; const float* b4  = (const float*)d_in[24];
    const float* w5  = (const float*)d_in[25]; const float* b5  = (const float*)d_in[26];
    const float* fcw = (const float*)d_in[27]; const float* fcb = (const float*)d_in[28];
    float* out = (float*)d_out;
    float* ws  = (float*)d_ws;

    // Workspace layout (floats). xg region is reused by `wave` after the LSTM.
    float* xg_f  = ws;                       //  4,243,456
    float* xg_r  = ws + 4243456;             //  4,243,456
    float* wave  = ws;                       // 12,730,368 (reuses xg region)
    float* X     = ws + 12730368;            //  2,121,728 (dead after wave_kernel)
    float* y2    = ws + 14852096;            //  2,113,536
    float* y3    = ws + 16965632;            //    524,288
    float* stats = ws + 18012160;            //      1,536 (BN1 s/s2)
    float* m1 = ws + 18013696; float* r1 = m1 + 768;
    float* tpart  = r1 + 768;                //      2,048 (tail partials)
    float* stats2 = tpart + 2048;            //        256 (BN2 raw s/s2)
    float* stats3 = stats2 + 256;            //         64 (BN3 raw s/s2)
    // Folded weights live in the dead X region (X only read by wave_kernel):
    float* w2t  = X;                  // 294,912
    float* b2t  = X + 294912;         //     128
    float* w3t  = X + 295040;         //  20,480
    float* b3t  = X + 315520;         //      32
    float* w4t  = X + 315552;         //   1,536
    float* b4t  = X + 317088;         //      16
    // fp16 Whh lives in the y2 region (written by packw, read by lstm, then
    // y2 is overwritten by conv2 long after lstm completes):
    h2* w16f = (h2*)y2;               //  8,192 u32
    h2* w16r = (h2*)(y2 + 8192);      //  8,192 u32

    // 0) pack Whh to fp16 pairs
    packw_kernel<<<dim3(1), 256, 0, stream>>>(whf, whr, w16f, w16r);
    // 1) input projections + zero BN1/BN2/BN3 stats
    xg_kernel<<<dim3(65, 32), 256, 0, stream>>>(x, wif, bf, wir, br, xg_f, xg_r,
                                                stats, stats2);
    // 2) bidirectional LSTM recurrence -> X (fp16 weights via v_dot2)
    lstm_kernel<<<dim3(64), 128, 0, stream>>>(xg_f, xg_r, w16f, w16r, X);
    // 3) wave module -> wave (raw), fused BN1 partial stats
    wave_kernel<<<dim3(3, CCH, B_), 256, 0, stream>>>(X, bw, bb, wave, stats);
    bn1_finalize_kernel<<<dim3(1), 768, 0, stream>>>(stats, m1, r1);
    // 4) fold BN1 into conv2 weights; conv2 on raw wave (+BN2 stats)
    bnfold2_kernel<<<dim3(128), 256, 0, stream>>>(w2, b2, m1, r1, g1, be1, w2t, b2t);
    conv2_kernel<<<dim3(32, 3, 8), 256, 0, stream>>>(wave, w2t, b2t, y2, stats2);
    // 5) fold BN2 (inline finalize) into conv3; conv3 (+BN3 stats)
    bnfold3_kernel<<<dim3(32), 256, 0, stream>>>(w3, b3, stats2, g2, be2, w3t, b3t);
    conv3_kernel<<<dim3(32, 2, 4), 256, 0, stream>>>(y2, w3t, b3t, y3, stats3);
    // 6) fold BN3 (inline finalize) into conv4 weights
    bnfold4_kernel<<<dim3(16), 128, 0, stream>>>(w4, b4, stats3, g3, be3, w4t, b4t);
    // 7) fused conv4 + DWT + conv5 + per-(b,ch) stats (no y4/y5 materialization)
    tail_fused_kernel<<<dim3(B_), 512, 0, stream>>>(y3, w4t, b4t, w5, b5,
                                                    stats3, g3, be3, tpart);
    // 8) BN4/BN5 stats + pooling + FC
    tail_final_kernel<<<dim3(1), 512, 0, stream>>>(tpart, g4, be4, g5, be5, fcw, fcb, out);
}